// Round 7
// baseline (495.798 us; speedup 1.0000x reference)
//
#include <hip/hip_runtime.h>
#include <hip/hip_bf16.h>

typedef __attribute__((ext_vector_type(8))) short bf16x8;
typedef __attribute__((ext_vector_type(4))) float f32x4;
typedef __attribute__((ext_vector_type(16))) float f32x16;
typedef __attribute__((ext_vector_type(4))) unsigned short u16x4;

#define MFMA16(a, b, c) __builtin_amdgcn_mfma_f32_16x16x32_bf16(a, b, c, 0, 0, 0)
#define MFMA32(a, b, c) __builtin_amdgcn_mfma_f32_32x32x16_bf16(a, b, c, 0, 0, 0)

#define SCALE 0.21022410381342865f /* 512^(-1/4) */

__device__ __forceinline__ unsigned short f2bf(float f) {
    union { float f; unsigned u; } v; v.f = f;
    unsigned r = v.u + 0x7FFF + ((v.u >> 16) & 1);
    return (unsigned short)(r >> 16);
}

__device__ __forceinline__ unsigned cvtpk(float lo, float hi) {
    unsigned r;
    asm("v_cvt_pk_bf16_f32 %0, %1, %2" : "=v"(r) : "v"(lo), "v"(hi));
    return r;
}

typedef __attribute__((address_space(3))) void lds_void;
typedef const __attribute__((address_space(1))) void gbl_void;
__device__ __forceinline__ void g2l16(const void* g, void* l) {
    __builtin_amdgcn_global_load_lds((gbl_void*)g, (lds_void*)l, 16, 0, 0);
}

#define PHASE_BARRIER() do { \
    asm volatile("s_waitcnt vmcnt(0) lgkmcnt(0)" ::: "memory"); \
    __builtin_amdgcn_s_barrier(); \
    __builtin_amdgcn_sched_barrier(0); \
} while (0)

// ---------------------------------------------------------------- GroupNorm
__global__ __launch_bounds__(256) void gn_kernel(
    const float* __restrict__ x, const float* __restrict__ gamma,
    const float* __restrict__ beta, unsigned short* __restrict__ xn)
{
    int b = blockIdx.x >> 5, g = blockIdx.x & 31;
    int t = threadIdx.x;
    const float4* xf4 = (const float4*)x;
    size_t base4 = (size_t)b * (4096 * 128) + g * 4;

    float s = 0.f, ss = 0.f;
    for (int i = 0; i < 64; ++i) {
        int flat = i * 256 + t;
        int hw = flat >> 2, c4 = flat & 3;
        float4 v = xf4[base4 + (size_t)hw * 128 + c4];
        s  += v.x + v.y + v.z + v.w;
        ss += v.x * v.x + v.y * v.y + v.z * v.z + v.w * v.w;
    }
    for (int m = 32; m >= 1; m >>= 1) { s += __shfl_xor(s, m); ss += __shfl_xor(ss, m); }
    __shared__ float rs_[4], rss_[4];
    int wv = t >> 6;
    if ((t & 63) == 0) { rs_[wv] = s; rss_[wv] = ss; }
    __syncthreads();
    float tot  = rs_[0] + rs_[1] + rs_[2] + rs_[3];
    float tot2 = rss_[0] + rss_[1] + rss_[2] + rss_[3];
    float mean = tot * (1.f / 65536.f);
    float var  = tot2 * (1.f / 65536.f) - mean * mean;
    float rstd = rsqrtf(var + 1e-6f);

    const float4* g4 = (const float4*)gamma;
    const float4* b4 = (const float4*)beta;
    for (int i = 0; i < 64; ++i) {
        int flat = i * 256 + t;
        int hw = flat >> 2, c4 = flat & 3;
        float4 v  = xf4[base4 + (size_t)hw * 128 + c4];
        float4 gm = g4[g * 4 + c4], bt = b4[g * 4 + c4];
        u16x4 o;
        o.x = f2bf((v.x - mean) * rstd * gm.x + bt.x);
        o.y = f2bf((v.y - mean) * rstd * gm.y + bt.y);
        o.z = f2bf((v.z - mean) * rstd * gm.z + bt.z);
        o.w = f2bf((v.w - mean) * rstd * gm.w + bt.w);
        size_t m_ = (size_t)(b * 4096 + hw);
        *(u16x4*)&xn[m_ * 512 + g * 16 + c4 * 4] = o;
    }
}

// ------------------------------------------------- weight prep: W^T as bf16
__global__ __launch_bounds__(256) void wprep(
    const float* __restrict__ Wq, const float* __restrict__ Wk,
    const float* __restrict__ Wv, const float* __restrict__ Wp,
    unsigned short* __restrict__ wqkvt, unsigned short* __restrict__ wpt)
{
    int idx = blockIdx.x * 256 + threadIdx.x; // 1,048,576 total
    if (idx < 786432) {
        int n = idx >> 9, k = idx & 511;
        int j = n >> 9, nn = n & 511;
        const float* W = (j == 0) ? Wq : (j == 1) ? Wk : Wv;
        wqkvt[idx] = f2bf(W[k * 512 + nn]);
    } else {
        int i2 = idx - 786432;
        int n = i2 >> 9, k = i2 & 511;
        wpt[i2] = f2bf(Wp[k * 512 + n]);
    }
}

// ------------------------------------------------------------- bf16 GEMM
template <int MODE>
__global__ __launch_bounds__(256) void gemm_kernel(
    const unsigned short* __restrict__ A, const unsigned short* __restrict__ Bt,
    const float* __restrict__ bias_q, const float* __restrict__ bias_k,
    const float* __restrict__ bias_v, const float* __restrict__ bias_p,
    const float* __restrict__ resid,
    unsigned short* __restrict__ Cbf, float* __restrict__ Cf)
{
    const int K = 512;
    int m0 = blockIdx.x * 128;
    int n0 = blockIdx.y * 128;
    int t = threadIdx.x;
    int l = t & 63, w = t >> 6;
    int wm = w >> 1, wn = w & 1;
    int lr = l & 15, lg = l >> 4;

    __shared__ unsigned short As[128][72];
    __shared__ unsigned short Bs[128][72];

    f32x4 acc[4][4];
    for (int i = 0; i < 4; ++i)
        for (int j = 0; j < 4; ++j) acc[i][j] = f32x4{0.f, 0.f, 0.f, 0.f};

    for (int k0 = 0; k0 < K; k0 += 64) {
        for (int c = 0; c < 4; ++c) {
            int flat = c * 256 + t;
            int row = flat >> 3, kc = (flat & 7) * 8;
            *(bf16x8*)&As[row][kc] = *(const bf16x8*)&A[(size_t)(m0 + row) * K + k0 + kc];
            *(bf16x8*)&Bs[row][kc] = *(const bf16x8*)&Bt[(size_t)(n0 + row) * K + k0 + kc];
        }
        __syncthreads();
        for (int ks = 0; ks < 2; ++ks) {
            bf16x8 af[4], bfr[4];
            for (int mi = 0; mi < 4; ++mi)
                af[mi] = *(bf16x8*)&As[wm * 64 + mi * 16 + lr][ks * 32 + lg * 8];
            for (int ni = 0; ni < 4; ++ni)
                bfr[ni] = *(bf16x8*)&Bs[wn * 64 + ni * 16 + lr][ks * 32 + lg * 8];
            for (int mi = 0; mi < 4; ++mi)
                for (int ni = 0; ni < 4; ++ni)
                    acc[mi][ni] = MFMA16(af[mi], bfr[ni], acc[mi][ni]);
        }
        __syncthreads();
    }

    for (int mi = 0; mi < 4; ++mi)
        for (int ni = 0; ni < 4; ++ni)
            for (int r = 0; r < 4; ++r) {
                int row = m0 + wm * 64 + mi * 16 + lg * 4 + r;
                int col = n0 + wn * 64 + ni * 16 + lr;
                float val = acc[mi][ni][r];
                if (MODE == 0) {
                    float bias, scl;
                    if (col < 512)       { bias = bias_q[col];        scl = SCALE; }
                    else if (col < 1024) { bias = bias_k[col - 512];  scl = SCALE; }
                    else                 { bias = bias_v[col - 1024]; scl = 1.0f;  }
                    Cbf[(size_t)row * 1536 + col] = f2bf((val + bias) * scl);
                } else {
                    Cf[(size_t)row * 512 + col] =
                        val + bias_p[col] + resid[(size_t)row * 512 + col];
                }
            }
}

// ------------------------------------------------ V transpose to [b][d][n]
__global__ __launch_bounds__(256) void vtrans(
    const unsigned short* __restrict__ qkv, unsigned short* __restrict__ vT)
{
    int n0 = blockIdx.x * 64, d0 = blockIdx.y * 64, b = blockIdx.z;
    int t = threadIdx.x;
    __shared__ unsigned short tile[64][72];
    for (int c = 0; c < 2; ++c) {
        int flat = c * 256 + t;
        int r = flat >> 3, cc = (flat & 7) * 8;
        *(bf16x8*)&tile[r][cc] =
            *(const bf16x8*)&qkv[(size_t)(b * 4096 + n0 + r) * 1536 + 1024 + d0 + cc];
    }
    __syncthreads();
    for (int c = 0; c < 2; ++c) {
        int flat = c * 256 + t;
        int dr = flat >> 3, nc = (flat & 7) * 8;
        bf16x8 v;
        for (int j = 0; j < 8; ++j) v[j] = (short)tile[nc + j][dr];
        *(bf16x8*)&vT[((size_t)b * 512 + d0 + dr) * 4096 + n0 + nc] = v;
    }
}

// ------------------------------------------------------- flash attention v7
// QBLK=64, KVBLK=128, 8 waves = (qh 0..1, kc 0..3), 256 blocks (1/CU).
// 32x32x16 MFMA, swapped QK^T: S^T[kv][q] = mfma(A=K, B=Q) -> softmax is
// lane-local (lane owns one q-column, 16 kv rows). P -> LDS (cvt_pk u32).
// PV: wave w owns d-slice; O = 4 x f32x16 = 64 regs.
// Staging: half-D 64KB chunks, 2 ping-pong buffers, 4 phases/tile:
//   P1: QK-d0(buf0)        | stage K.d1 -> buf1
//   P2: QK-d1(buf1)+softmax| stage V.d0 -> buf0
//   P3: PV-d0(buf0)        | stage V.d1 -> buf1
//   P4: PV-d1(buf1)        | stage K'.d0 -> buf0
// Each phase ends: vmcnt(0)+lgkmcnt(0) + s_barrier (chunk window = full phase).
__global__ __launch_bounds__(512, 1) void attn_kernel(
    const unsigned short* __restrict__ qkv, // [16384][1536] (q|k|v)
    const unsigned short* __restrict__ vT,  // [4][512][4096]
    unsigned short* __restrict__ out)       // [16384][512]
{
    int wg = blockIdx.x;
    int xcd = wg & 7;
    int b = xcd >> 1;
    int n0 = ((wg >> 3) + (xcd & 1) * 32) * 64;

    int t = threadIdx.x, l = t & 63, w = t >> 6;
    int lq = l & 31, hi = l >> 5;
    int qh = w & 1, kc = w >> 1;

    __shared__ __align__(16) unsigned short buf0[32768];  // 64 KB
    __shared__ __align__(16) unsigned short buf1[32768];  // 64 KB
    __shared__ __align__(16) unsigned short Pl[64 * 136]; // 17 KB (stride 136 = 17*16B)
    __shared__ float Lp[4][64];

    // ---- Q B-fragments: lane holds Q[q = n0+qh*32+lq][k = s*16 + hi*8 + j]
    bf16x8 qf[32];
    {
        const unsigned short* qrow =
            qkv + (size_t)(b * 4096 + n0 + qh * 32 + lq) * 1536 + hi * 8;
#pragma unroll
        for (int s = 0; s < 32; ++s)
            qf[s] = *(const bf16x8*)&qrow[s * 16];
    }

    f32x16 oc00, oc01, oc10, oc11, sa, sb;
#pragma unroll
    for (int i = 0; i < 16; ++i) {
        oc00[i] = 0.f; oc01[i] = 0.f; oc10[i] = 0.f; oc11[i] = 0.f;
        sa[i] = 0.f; sb[i] = 0.f;
    }
    float l_acc = 0.f;

    // staging: K chunk [128 kv][256 d-half] (32 units/row), V chunk [256 d][128 kv]
    // (16 units/row); both XOR-swizzled by (row&7) via pre-swizzled source.
    auto stageK = [&](int tile, int pass, unsigned short* dst) {
        int kv0 = tile * 128;
#pragma unroll
        for (int c = 0; c < 8; ++c) {
            int flat = c * 512 + t;
            int row = flat >> 5, u = flat & 31;
            g2l16(qkv + (size_t)(b * 4096 + kv0 + row) * 1536 + 512 + pass * 256 +
                      ((u ^ (row & 7)) << 3),
                  dst + (flat << 3));
        }
    };
    auto stageV = [&](int tile, int pass, unsigned short* dst) {
        int kv0 = tile * 128;
#pragma unroll
        for (int c = 0; c < 8; ++c) {
            int flat = c * 512 + t;
            int row = flat >> 4, u = flat & 15;
            g2l16(vT + ((size_t)b * 512 + pass * 256 + row) * 4096 + kv0 +
                      ((u ^ (row & 7)) << 3),
                  dst + (flat << 3));
        }
    };

    stageK(0, 0, buf0);
    PHASE_BARRIER();

    const int krow = kc * 32 + lq;      // K A-frag row within tile
    const int rsw = krow & 7;
    const int vrow = w * 32 + lq;       // V B-frag row (d_local)
    const int vsw = lq & 7;
    const int q = qh * 32 + lq;

    for (int tile = 0; tile < 32; ++tile) {
        // ---- P1: QK pass 0 (buf0 = K.d0) ; stage K.d1 -> buf1
        stageK(tile, 1, buf1);
        __builtin_amdgcn_s_setprio(1);
#pragma unroll
        for (int ks = 0; ks < 16; ks += 2) {
            bf16x8 ka = *(const bf16x8*)&buf0[(krow * 32 + ((2 * ks + hi) ^ rsw)) << 3];
            sa = MFMA32(ka, qf[ks], sa);
            bf16x8 kb = *(const bf16x8*)&buf0[(krow * 32 + ((2 * ks + 2 + hi) ^ rsw)) << 3];
            sb = MFMA32(kb, qf[ks + 1], sb);
        }
        __builtin_amdgcn_s_setprio(0);
        PHASE_BARRIER();

        // ---- P2: QK pass 1 (buf1 = K.d1) ; stage V.d0 -> buf0 ; softmax
        stageV(tile, 0, buf0);
        __builtin_amdgcn_s_setprio(1);
#pragma unroll
        for (int ks = 0; ks < 16; ks += 2) {
            bf16x8 ka = *(const bf16x8*)&buf1[(krow * 32 + ((2 * ks + hi) ^ rsw)) << 3];
            sa = MFMA32(ka, qf[16 + ks], sa);
            bf16x8 kb = *(const bf16x8*)&buf1[(krow * 32 + ((2 * ks + 2 + hi) ^ rsw)) << 3];
            sb = MFMA32(kb, qf[16 + ks + 1], sb);
        }
        __builtin_amdgcn_s_setprio(0);

        // softmax: lane owns q-col, 16 kv rows (kv = kc*32 + (r&3)+8*(r>>2)+4*hi)
        {
            f32x16 s = sa + sb;
            float p[16];
            float ls = 0.f;
#pragma unroll
            for (int r = 0; r < 16; ++r) { p[r] = __expf(s[r]); ls += p[r]; }
            ls += __shfl_xor(ls, 32);
            l_acc += ls;
#pragma unroll
            for (int g = 0; g < 4; ++g) {
                unsigned w0 = cvtpk(p[4 * g], p[4 * g + 1]);
                unsigned w1 = cvtpk(p[4 * g + 2], p[4 * g + 3]);
                int kvb = kc * 32 + 8 * g + 4 * hi;
                *(unsigned*)&Pl[q * 136 + kvb] = w0;
                *(unsigned*)&Pl[q * 136 + kvb + 2] = w1;
            }
#pragma unroll
            for (int i = 0; i < 16; ++i) { sa[i] = 0.f; sb[i] = 0.f; }
        }
        PHASE_BARRIER();

        // ---- P3: PV pass 0 (buf0 = V.d0) ; stage V.d1 -> buf1
        stageV(tile, 1, buf1);
        __builtin_amdgcn_s_setprio(1);
#pragma unroll
        for (int ks = 0; ks < 8; ++ks) {
            bf16x8 a0 = *(const bf16x8*)&Pl[lq * 136 + ks * 16 + hi * 8];
            bf16x8 a1 = *(const bf16x8*)&Pl[(32 + lq) * 136 + ks * 16 + hi * 8];
            bf16x8 vb = *(const bf16x8*)&buf0[(vrow * 16 + ((2 * ks + hi) ^ vsw)) << 3];
            oc00 = MFMA32(a0, vb, oc00);
            oc10 = MFMA32(a1, vb, oc10);
        }
        __builtin_amdgcn_s_setprio(0);
        PHASE_BARRIER();

        // ---- P4: PV pass 1 (buf1 = V.d1) ; stage K(t+1).d0 -> buf0
        if (tile + 1 < 32) stageK(tile + 1, 0, buf0);
        __builtin_amdgcn_s_setprio(1);
#pragma unroll
        for (int ks = 0; ks < 8; ++ks) {
            bf16x8 a0 = *(const bf16x8*)&Pl[lq * 136 + ks * 16 + hi * 8];
            bf16x8 a1 = *(const bf16x8*)&Pl[(32 + lq) * 136 + ks * 16 + hi * 8];
            bf16x8 vb = *(const bf16x8*)&buf1[(vrow * 16 + ((2 * ks + hi) ^ vsw)) << 3];
            oc01 = MFMA32(a0, vb, oc01);
            oc11 = MFMA32(a1, vb, oc11);
        }
        __builtin_amdgcn_s_setprio(0);
        PHASE_BARRIER();
    }

    // ---- merge l partials across kc, normalize, store
    if (l < 32) Lp[kc][qh * 32 + lq] = l_acc;
    PHASE_BARRIER();

#pragma unroll
    for (int r = 0; r < 16; ++r) {
        int row0 = (r & 3) + 8 * (r >> 2) + 4 * hi;
        float lt0 = Lp[0][row0] + Lp[1][row0] + Lp[2][row0] + Lp[3][row0];
        float inv0 = 1.0f / lt0;
        size_t o0 = (size_t)(b * 4096 + n0 + row0) * 512 + w * 32 + lq;
        out[o0]       = f2bf(oc00[r] * inv0);
        out[o0 + 256] = f2bf(oc01[r] * inv0);
        int row1 = 32 + row0;
        float lt1 = Lp[0][row1] + Lp[1][row1] + Lp[2][row1] + Lp[3][row1];
        float inv1 = 1.0f / lt1;
        size_t o1 = (size_t)(b * 4096 + n0 + row1) * 512 + w * 32 + lq;
        out[o1]       = f2bf(oc10[r] * inv1);
        out[o1 + 256] = f2bf(oc11[r] * inv1);
    }
}

// --------------------------------------------------------------- launcher
extern "C" void kernel_launch(void* const* d_in, const int* in_sizes, int n_in,
                              void* d_out, int out_size, void* d_ws, size_t ws_size,
                              hipStream_t stream)
{
    const float* x     = (const float*)d_in[0];
    const float* gamma = (const float*)d_in[1];
    const float* beta  = (const float*)d_in[2];
    const float* Wq = (const float*)d_in[3];
    const float* bq = (const float*)d_in[4];
    const float* Wk = (const float*)d_in[5];
    const float* bk = (const float*)d_in[6];
    const float* Wv = (const float*)d_in[7];
    const float* bv = (const float*)d_in[8];
    const float* Wp = (const float*)d_in[9];
    const float* bp = (const float*)d_in[10];
    float* out = (float*)d_out;

    unsigned short* xn    = (unsigned short*)d_ws;                 // 16384*512
    unsigned short* wqkvt = xn + (size_t)16384 * 512;              // 1536*512
    unsigned short* wpt   = wqkvt + (size_t)1536 * 512;            // 512*512
    unsigned short* qkv   = wpt + (size_t)512 * 512;               // 16384*1536
    unsigned short* vT    = qkv + (size_t)16384 * 1536;            // 4*512*4096
    unsigned short* attn  = vT + (size_t)4 * 512 * 4096;           // 16384*512

    gn_kernel<<<dim3(128), dim3(256), 0, stream>>>(x, gamma, beta, xn);
    wprep<<<dim3(4096), dim3(256), 0, stream>>>(Wq, Wk, Wv, Wp, wqkvt, wpt);
    gemm_kernel<0><<<dim3(128, 12), dim3(256), 0, stream>>>(
        xn, wqkvt, bq, bk, bv, nullptr, nullptr, qkv, nullptr);
    vtrans<<<dim3(64, 8, 4), dim3(256), 0, stream>>>(qkv, vT);
    attn_kernel<<<dim3(256), dim3(512), 0, stream>>>(qkv, vT, attn);
    gemm_kernel<1><<<dim3(128, 4), dim3(256), 0, stream>>>(
        attn, wpt, nullptr, nullptr, nullptr, bp, x, nullptr, out);
}

// Round 8
// 370.357 us; speedup vs baseline: 1.3387x; 1.3387x over previous
//
#include <hip/hip_runtime.h>
#include <hip/hip_bf16.h>

typedef __attribute__((ext_vector_type(8))) short bf16x8;
typedef __attribute__((ext_vector_type(4))) float f32x4;
typedef __attribute__((ext_vector_type(4))) unsigned short u16x4;

#define MFMA16(a, b, c) __builtin_amdgcn_mfma_f32_16x16x32_bf16(a, b, c, 0, 0, 0)

#define SCALE 0.21022410381342865f /* 512^(-1/4) */

__device__ __forceinline__ unsigned short f2bf(float f) {
    union { float f; unsigned u; } v; v.f = f;
    unsigned r = v.u + 0x7FFF + ((v.u >> 16) & 1);
    return (unsigned short)(r >> 16);
}

typedef __attribute__((address_space(3))) void lds_void;
typedef const __attribute__((address_space(1))) void gbl_void;
__device__ __forceinline__ void g2l16(const void* g, void* l) {
    __builtin_amdgcn_global_load_lds((gbl_void*)g, (lds_void*)l, 16, 0, 0);
}

#define PHASE_BARRIER() do { \
    asm volatile("s_waitcnt vmcnt(0) lgkmcnt(0)" ::: "memory"); \
    __builtin_amdgcn_s_barrier(); \
    __builtin_amdgcn_sched_barrier(0); \
} while (0)

// ---------------------------------------------------------------- GroupNorm
__global__ __launch_bounds__(256) void gn_kernel(
    const float* __restrict__ x, const float* __restrict__ gamma,
    const float* __restrict__ beta, unsigned short* __restrict__ xn)
{
    int b = blockIdx.x >> 5, g = blockIdx.x & 31;
    int t = threadIdx.x;
    const float4* xf4 = (const float4*)x;
    size_t base4 = (size_t)b * (4096 * 128) + g * 4;

    float s = 0.f, ss = 0.f;
    for (int i = 0; i < 64; ++i) {
        int flat = i * 256 + t;
        int hw = flat >> 2, c4 = flat & 3;
        float4 v = xf4[base4 + (size_t)hw * 128 + c4];
        s  += v.x + v.y + v.z + v.w;
        ss += v.x * v.x + v.y * v.y + v.z * v.z + v.w * v.w;
    }
    for (int m = 32; m >= 1; m >>= 1) { s += __shfl_xor(s, m); ss += __shfl_xor(ss, m); }
    __shared__ float rs_[4], rss_[4];
    int wv = t >> 6;
    if ((t & 63) == 0) { rs_[wv] = s; rss_[wv] = ss; }
    __syncthreads();
    float tot  = rs_[0] + rs_[1] + rs_[2] + rs_[3];
    float tot2 = rss_[0] + rss_[1] + rss_[2] + rss_[3];
    float mean = tot * (1.f / 65536.f);
    float var  = tot2 * (1.f / 65536.f) - mean * mean;
    float rstd = rsqrtf(var + 1e-6f);

    const float4* g4 = (const float4*)gamma;
    const float4* b4 = (const float4*)beta;
    for (int i = 0; i < 64; ++i) {
        int flat = i * 256 + t;
        int hw = flat >> 2, c4 = flat & 3;
        float4 v  = xf4[base4 + (size_t)hw * 128 + c4];
        float4 gm = g4[g * 4 + c4], bt = b4[g * 4 + c4];
        u16x4 o;
        o.x = f2bf((v.x - mean) * rstd * gm.x + bt.x);
        o.y = f2bf((v.y - mean) * rstd * gm.y + bt.y);
        o.z = f2bf((v.z - mean) * rstd * gm.z + bt.z);
        o.w = f2bf((v.w - mean) * rstd * gm.w + bt.w);
        size_t m_ = (size_t)(b * 4096 + hw);
        *(u16x4*)&xn[m_ * 512 + g * 16 + c4 * 4] = o;
    }
}

// ------------------------------------------------- weight prep: W^T as bf16
__global__ __launch_bounds__(256) void wprep(
    const float* __restrict__ Wq, const float* __restrict__ Wk,
    const float* __restrict__ Wv, const float* __restrict__ Wp,
    unsigned short* __restrict__ wqkvt, unsigned short* __restrict__ wpt)
{
    int idx = blockIdx.x * 256 + threadIdx.x; // 1,048,576 total
    if (idx < 786432) {
        int n = idx >> 9, k = idx & 511;
        int j = n >> 9, nn = n & 511;
        const float* W = (j == 0) ? Wq : (j == 1) ? Wk : Wv;
        wqkvt[idx] = f2bf(W[k * 512 + nn]);
    } else {
        int i2 = idx - 786432;
        int n = i2 >> 9, k = i2 & 511;
        wpt[i2] = f2bf(Wp[k * 512 + n]);
    }
}

// ------------------------------------------------------------- bf16 GEMM
template <int MODE>
__global__ __launch_bounds__(256) void gemm_kernel(
    const unsigned short* __restrict__ A, const unsigned short* __restrict__ Bt,
    const float* __restrict__ bias_q, const float* __restrict__ bias_k,
    const float* __restrict__ bias_v, const float* __restrict__ bias_p,
    const float* __restrict__ resid,
    unsigned short* __restrict__ Cbf, float* __restrict__ Cf)
{
    const int K = 512;
    int m0 = blockIdx.x * 128;
    int n0 = blockIdx.y * 128;
    int t = threadIdx.x;
    int l = t & 63, w = t >> 6;
    int wm = w >> 1, wn = w & 1;
    int lr = l & 15, lg = l >> 4;

    __shared__ unsigned short As[128][72];
    __shared__ unsigned short Bs[128][72];

    f32x4 acc[4][4];
    for (int i = 0; i < 4; ++i)
        for (int j = 0; j < 4; ++j) acc[i][j] = f32x4{0.f, 0.f, 0.f, 0.f};

    for (int k0 = 0; k0 < K; k0 += 64) {
        for (int c = 0; c < 4; ++c) {
            int flat = c * 256 + t;
            int row = flat >> 3, kc = (flat & 7) * 8;
            *(bf16x8*)&As[row][kc] = *(const bf16x8*)&A[(size_t)(m0 + row) * K + k0 + kc];
            *(bf16x8*)&Bs[row][kc] = *(const bf16x8*)&Bt[(size_t)(n0 + row) * K + k0 + kc];
        }
        __syncthreads();
        for (int ks = 0; ks < 2; ++ks) {
            bf16x8 af[4], bfr[4];
            for (int mi = 0; mi < 4; ++mi)
                af[mi] = *(bf16x8*)&As[wm * 64 + mi * 16 + lr][ks * 32 + lg * 8];
            for (int ni = 0; ni < 4; ++ni)
                bfr[ni] = *(bf16x8*)&Bs[wn * 64 + ni * 16 + lr][ks * 32 + lg * 8];
            for (int mi = 0; mi < 4; ++mi)
                for (int ni = 0; ni < 4; ++ni)
                    acc[mi][ni] = MFMA16(af[mi], bfr[ni], acc[mi][ni]);
        }
        __syncthreads();
    }

    for (int mi = 0; mi < 4; ++mi)
        for (int ni = 0; ni < 4; ++ni)
            for (int r = 0; r < 4; ++r) {
                int row = m0 + wm * 64 + mi * 16 + lg * 4 + r;
                int col = n0 + wn * 64 + ni * 16 + lr;
                float val = acc[mi][ni][r];
                if (MODE == 0) {
                    float bias, scl;
                    if (col < 512)       { bias = bias_q[col];        scl = SCALE; }
                    else if (col < 1024) { bias = bias_k[col - 512];  scl = SCALE; }
                    else                 { bias = bias_v[col - 1024]; scl = 1.0f;  }
                    Cbf[(size_t)row * 1536 + col] = f2bf((val + bias) * scl);
                } else {
                    Cf[(size_t)row * 512 + col] =
                        val + bias_p[col] + resid[(size_t)row * 512 + col];
                }
            }
}

// ------------------------------------------------ V transpose to [b][d][n]
__global__ __launch_bounds__(256) void vtrans(
    const unsigned short* __restrict__ qkv, unsigned short* __restrict__ vT)
{
    int n0 = blockIdx.x * 64, d0 = blockIdx.y * 64, b = blockIdx.z;
    int t = threadIdx.x;
    __shared__ unsigned short tile[64][72];
    for (int c = 0; c < 2; ++c) {
        int flat = c * 256 + t;
        int r = flat >> 3, cc = (flat & 7) * 8;
        *(bf16x8*)&tile[r][cc] =
            *(const bf16x8*)&qkv[(size_t)(b * 4096 + n0 + r) * 1536 + 1024 + d0 + cc];
    }
    __syncthreads();
    for (int c = 0; c < 2; ++c) {
        int flat = c * 256 + t;
        int dr = flat >> 3, nc = (flat & 7) * 8;
        bf16x8 v;
        for (int j = 0; j < 8; ++j) v[j] = (short)tile[nc + j][dr];
        *(bf16x8*)&vT[((size_t)b * 512 + d0 + dr) * 4096 + n0 + nc] = v;
    }
}

// ------------------------------------------------------------ QK^T + exp
// 128x128 tile, m97-style: g2l16 staging, XOR-swizzled LDS, dbuf, 1 bar/step.
// Grid (32 m, 32 n, 2 chunk-batches), 256 thr. K = 512 (8 steps).
// Epilogue: P = exp(S) -> row partial sums (lpart) -> LDS repack -> coalesced
// bf16 stores of P[bb][4096][4096].
__global__ __launch_bounds__(256) void qk_kernel(
    const unsigned short* __restrict__ qkv, unsigned short* __restrict__ P,
    float* __restrict__ lpart, int b0)
{
    int m0 = blockIdx.x * 128, n0 = blockIdx.y * 128, bb = blockIdx.z;
    int b = b0 + bb;
    int t = threadIdx.x, l = t & 63, w = t >> 6;
    int wm = w >> 1, wn = w & 1;
    int lr = l & 15, lg = l >> 4;

    __shared__ __align__(16) unsigned short As[2][8192];  // 2 x 16 KB
    __shared__ __align__(16) unsigned short Bs[2][8192];

    const unsigned short* A_ = qkv + (size_t)(b * 4096 + m0) * 1536;        // q
    const unsigned short* B_ = qkv + (size_t)(b * 4096 + n0) * 1536 + 512;  // k

    auto stage = [&](int k0, int buf) {
#pragma unroll
        for (int c = 0; c < 4; ++c) {
            int flat = c * 256 + t;
            int row = flat >> 3, u = flat & 7;
            g2l16(A_ + (size_t)row * 1536 + k0 + ((u ^ (row & 7)) << 3),
                  &As[buf][flat << 3]);
        }
#pragma unroll
        for (int c = 0; c < 4; ++c) {
            int flat = c * 256 + t;
            int row = flat >> 3, u = flat & 7;
            g2l16(B_ + (size_t)row * 1536 + k0 + ((u ^ (row & 7)) << 3),
                  &Bs[buf][flat << 3]);
        }
    };

    f32x4 acc[4][4];
#pragma unroll
    for (int i = 0; i < 4; ++i)
#pragma unroll
        for (int j = 0; j < 4; ++j) acc[i][j] = f32x4{0.f, 0.f, 0.f, 0.f};

    stage(0, 0);
    PHASE_BARRIER();

    int buf = 0;
    for (int s = 0; s < 8; ++s) {
        if (s < 7) stage((s + 1) * 64, buf ^ 1);
        const unsigned short* Al = As[buf];
        const unsigned short* Bl = Bs[buf];
        __builtin_amdgcn_s_setprio(1);
#pragma unroll
        for (int ks = 0; ks < 2; ++ks) {
            bf16x8 af[4], bfr[4];
#pragma unroll
            for (int mi = 0; mi < 4; ++mi) {
                int row = wm * 64 + mi * 16 + lr;
                af[mi] = *(const bf16x8*)&Al[(row * 8 + ((ks * 4 + lg) ^ (row & 7))) << 3];
            }
#pragma unroll
            for (int ni = 0; ni < 4; ++ni) {
                int row = wn * 64 + ni * 16 + lr;
                bfr[ni] = *(const bf16x8*)&Bl[(row * 8 + ((ks * 4 + lg) ^ (row & 7))) << 3];
            }
#pragma unroll
            for (int mi = 0; mi < 4; ++mi)
#pragma unroll
                for (int ni = 0; ni < 4; ++ni)
                    acc[mi][ni] = MFMA16(af[mi], bfr[ni], acc[mi][ni]);
        }
        __builtin_amdgcn_s_setprio(0);
        PHASE_BARRIER();
        buf ^= 1;
    }

    // ---- epilogue: exp, row partial sums, repack, store
    unsigned short* Pl = &As[0][0];  // 128 x 128 ushort = 32 KB (As is free)
#pragma unroll
    for (int mi = 0; mi < 4; ++mi)
#pragma unroll
        for (int r = 0; r < 4; ++r) {
            float p0 = __expf(acc[mi][0][r]);
            float p1 = __expf(acc[mi][1][r]);
            float p2 = __expf(acc[mi][2][r]);
            float p3 = __expf(acc[mi][3][r]);
            float s = p0 + p1 + p2 + p3;
            s += __shfl_xor(s, 1); s += __shfl_xor(s, 2);
            s += __shfl_xor(s, 4); s += __shfl_xor(s, 8);
            int row = wm * 64 + mi * 16 + lg * 4 + r;
            if (lr == 0)
                lpart[(size_t)(bb * 64 + blockIdx.y * 2 + wn) * 4096 + m0 + row] = s;
            Pl[row * 128 + wn * 64 + 0 * 16 + lr] = f2bf(p0);
            Pl[row * 128 + wn * 64 + 1 * 16 + lr] = f2bf(p1);
            Pl[row * 128 + wn * 64 + 2 * 16 + lr] = f2bf(p2);
            Pl[row * 128 + wn * 64 + 3 * 16 + lr] = f2bf(p3);
        }
    __syncthreads();
#pragma unroll
    for (int c = 0; c < 8; ++c) {
        int flat = c * 256 + t;
        int row = flat >> 4, u = flat & 15;
        *(bf16x8*)&P[((size_t)(bb * 4096 + m0 + row)) * 4096 + n0 + u * 8] =
            *(const bf16x8*)&Pl[row * 128 + u * 8];
    }
}

// ----------------------------------------------------- l reduce (64 slices)
__global__ __launch_bounds__(256) void lred_kernel(
    const float* __restrict__ lpart, float* __restrict__ lsum)
{
    int rr = blockIdx.x * 256 + threadIdx.x;  // 0..8191
    int bb = rr >> 12, r = rr & 4095;
    float s = 0.f;
#pragma unroll
    for (int sl = 0; sl < 64; ++sl)
        s += lpart[(size_t)(bb * 64 + sl) * 4096 + r];
    lsum[rr] = 1.0f / s;
}

// ------------------------------------------------------------ PV GEMM
// O[q][d] = (P . V) / l. 64x128 tile, K=4096 (64 steps), grid (64,4,2), 256 thr.
// A = P (stride 4096), Bt = vT (stride 4096). Epilogue: * linv, bf16 store.
__global__ __launch_bounds__(256) void pv_kernel(
    const unsigned short* __restrict__ P, const unsigned short* __restrict__ vT,
    const float* __restrict__ linv, unsigned short* __restrict__ outb, int b0)
{
    int m0 = blockIdx.x * 64, n0 = blockIdx.y * 128, bb = blockIdx.z;
    int b = b0 + bb;
    int t = threadIdx.x, l = t & 63, w = t >> 6;
    int wm = w >> 1, wn = w & 1;
    int lr = l & 15, lg = l >> 4;

    __shared__ __align__(16) unsigned short As[2][4096];  // 2 x 8 KB (64x64)
    __shared__ __align__(16) unsigned short Bs[2][8192];  // 2 x 16 KB (128x64)

    const unsigned short* A_ = P + (size_t)(bb * 4096 + m0) * 4096;
    const unsigned short* B_ = vT + ((size_t)b * 512 + n0) * 4096;

    auto stage = [&](int k0, int buf) {
#pragma unroll
        for (int c = 0; c < 2; ++c) {
            int flat = c * 256 + t;
            int row = flat >> 3, u = flat & 7;
            g2l16(A_ + (size_t)row * 4096 + k0 + ((u ^ (row & 7)) << 3),
                  &As[buf][flat << 3]);
        }
#pragma unroll
        for (int c = 0; c < 4; ++c) {
            int flat = c * 256 + t;
            int row = flat >> 3, u = flat & 7;
            g2l16(B_ + (size_t)row * 4096 + k0 + ((u ^ (row & 7)) << 3),
                  &Bs[buf][flat << 3]);
        }
    };

    f32x4 acc[2][4];
#pragma unroll
    for (int i = 0; i < 2; ++i)
#pragma unroll
        for (int j = 0; j < 4; ++j) acc[i][j] = f32x4{0.f, 0.f, 0.f, 0.f};

    stage(0, 0);
    PHASE_BARRIER();

    int buf = 0;
    for (int s = 0; s < 64; ++s) {
        if (s < 63) stage((s + 1) * 64, buf ^ 1);
        const unsigned short* Al = As[buf];
        const unsigned short* Bl = Bs[buf];
        __builtin_amdgcn_s_setprio(1);
#pragma unroll
        for (int ks = 0; ks < 2; ++ks) {
            bf16x8 af[2], bfr[4];
#pragma unroll
            for (int mi = 0; mi < 2; ++mi) {
                int row = wm * 32 + mi * 16 + lr;
                af[mi] = *(const bf16x8*)&Al[(row * 8 + ((ks * 4 + lg) ^ (row & 7))) << 3];
            }
#pragma unroll
            for (int ni = 0; ni < 4; ++ni) {
                int row = wn * 64 + ni * 16 + lr;
                bfr[ni] = *(const bf16x8*)&Bl[(row * 8 + ((ks * 4 + lg) ^ (row & 7))) << 3];
            }
#pragma unroll
            for (int mi = 0; mi < 2; ++mi)
#pragma unroll
                for (int ni = 0; ni < 4; ++ni)
                    acc[mi][ni] = MFMA16(af[mi], bfr[ni], acc[mi][ni]);
        }
        __builtin_amdgcn_s_setprio(0);
        PHASE_BARRIER();
        buf ^= 1;
    }

#pragma unroll
    for (int mi = 0; mi < 2; ++mi)
#pragma unroll
        for (int r = 0; r < 4; ++r) {
            int row = m0 + wm * 32 + mi * 16 + lg * 4 + r;
            float inv = linv[bb * 4096 + row];
#pragma unroll
            for (int ni = 0; ni < 4; ++ni) {
                int col = n0 + wn * 64 + ni * 16 + lr;
                outb[(size_t)(b * 4096 + row) * 512 + col] =
                    f2bf(acc[mi][ni][r] * inv);
            }
        }
}

// --------------------------------------------------------------- launcher
extern "C" void kernel_launch(void* const* d_in, const int* in_sizes, int n_in,
                              void* d_out, int out_size, void* d_ws, size_t ws_size,
                              hipStream_t stream)
{
    const float* x     = (const float*)d_in[0];
    const float* gamma = (const float*)d_in[1];
    const float* beta  = (const float*)d_in[2];
    const float* Wq = (const float*)d_in[3];
    const float* bq = (const float*)d_in[4];
    const float* Wk = (const float*)d_in[5];
    const float* bk = (const float*)d_in[6];
    const float* Wv = (const float*)d_in[7];
    const float* bv = (const float*)d_in[8];
    const float* Wp = (const float*)d_in[9];
    const float* bp = (const float*)d_in[10];
    float* out = (float*)d_out;

    unsigned short* xn    = (unsigned short*)d_ws;                 // 16384*512 (reused as attn out)
    unsigned short* wqkvt = xn + (size_t)16384 * 512;              // 1536*512
    unsigned short* wpt   = wqkvt + (size_t)1536 * 512;            // 512*512
    unsigned short* qkv   = wpt + (size_t)512 * 512;               // 16384*1536
    unsigned short* vT    = qkv + (size_t)16384 * 1536;            // 4*512*4096
    unsigned short* P     = vT + (size_t)4 * 512 * 4096;           // 2*4096*4096 (64MB)
    float* lpart = (float*)(P + (size_t)2 * 4096 * 4096);          // 128*4096 f32
    float* linv  = lpart + (size_t)128 * 4096;                     // 8192 f32

    gn_kernel<<<dim3(128), dim3(256), 0, stream>>>(x, gamma, beta, xn);
    wprep<<<dim3(4096), dim3(256), 0, stream>>>(Wq, Wk, Wv, Wp, wqkvt, wpt);
    gemm_kernel<0><<<dim3(128, 12), dim3(256), 0, stream>>>(
        xn, wqkvt, bq, bk, bv, nullptr, nullptr, qkv, nullptr);
    vtrans<<<dim3(64, 8, 4), dim3(256), 0, stream>>>(qkv, vT);

    for (int b0 = 0; b0 < 4; b0 += 2) {
        qk_kernel<<<dim3(32, 32, 2), dim3(256), 0, stream>>>(qkv, P, lpart, b0);
        lred_kernel<<<dim3(32), dim3(256), 0, stream>>>(lpart, linv);
        pv_kernel<<<dim3(64, 4, 2), dim3(256), 0, stream>>>(P, vT, linv, xn, b0);
    }

    gemm_kernel<1><<<dim3(128, 4), dim3(256), 0, stream>>>(
        xn, wpt, nullptr, nullptr, nullptr, bp, x, nullptr, out);
}

// Round 9
// 354.332 us; speedup vs baseline: 1.3992x; 1.0452x over previous
//
#include <hip/hip_runtime.h>
#include <hip/hip_bf16.h>

typedef __attribute__((ext_vector_type(8))) short bf16x8;
typedef __attribute__((ext_vector_type(4))) float f32x4;
typedef __attribute__((ext_vector_type(4))) unsigned short u16x4;

#define MFMA16(a, b, c) __builtin_amdgcn_mfma_f32_16x16x32_bf16(a, b, c, 0, 0, 0)

#define SCALE 0.21022410381342865f /* 512^(-1/4) */

__device__ __forceinline__ unsigned short f2bf(float f) {
    union { float f; unsigned u; } v; v.f = f;
    unsigned r = v.u + 0x7FFF + ((v.u >> 16) & 1);
    return (unsigned short)(r >> 16);
}

typedef __attribute__((address_space(3))) void lds_void;
typedef const __attribute__((address_space(1))) void gbl_void;
__device__ __forceinline__ void g2l16(const void* g, void* l) {
    __builtin_amdgcn_global_load_lds((gbl_void*)g, (lds_void*)l, 16, 0, 0);
}

#define PHASE_BARRIER() do { \
    asm volatile("s_waitcnt vmcnt(0) lgkmcnt(0)" ::: "memory"); \
    __builtin_amdgcn_s_barrier(); \
    __builtin_amdgcn_sched_barrier(0); \
} while (0)

// ---------------------------------------------------------------- GroupNorm
__global__ __launch_bounds__(256) void gn_kernel(
    const float* __restrict__ x, const float* __restrict__ gamma,
    const float* __restrict__ beta, unsigned short* __restrict__ xn)
{
    int b = blockIdx.x >> 5, g = blockIdx.x & 31;
    int t = threadIdx.x;
    const float4* xf4 = (const float4*)x;
    size_t base4 = (size_t)b * (4096 * 128) + g * 4;

    float s = 0.f, ss = 0.f;
    for (int i = 0; i < 64; ++i) {
        int flat = i * 256 + t;
        int hw = flat >> 2, c4 = flat & 3;
        float4 v = xf4[base4 + (size_t)hw * 128 + c4];
        s  += v.x + v.y + v.z + v.w;
        ss += v.x * v.x + v.y * v.y + v.z * v.z + v.w * v.w;
    }
    for (int m = 32; m >= 1; m >>= 1) { s += __shfl_xor(s, m); ss += __shfl_xor(ss, m); }
    __shared__ float rs_[4], rss_[4];
    int wv = t >> 6;
    if ((t & 63) == 0) { rs_[wv] = s; rss_[wv] = ss; }
    __syncthreads();
    float tot  = rs_[0] + rs_[1] + rs_[2] + rs_[3];
    float tot2 = rss_[0] + rss_[1] + rss_[2] + rss_[3];
    float mean = tot * (1.f / 65536.f);
    float var  = tot2 * (1.f / 65536.f) - mean * mean;
    float rstd = rsqrtf(var + 1e-6f);

    const float4* g4 = (const float4*)gamma;
    const float4* b4 = (const float4*)beta;
    for (int i = 0; i < 64; ++i) {
        int flat = i * 256 + t;
        int hw = flat >> 2, c4 = flat & 3;
        float4 v  = xf4[base4 + (size_t)hw * 128 + c4];
        float4 gm = g4[g * 4 + c4], bt = b4[g * 4 + c4];
        u16x4 o;
        o.x = f2bf((v.x - mean) * rstd * gm.x + bt.x);
        o.y = f2bf((v.y - mean) * rstd * gm.y + bt.y);
        o.z = f2bf((v.z - mean) * rstd * gm.z + bt.z);
        o.w = f2bf((v.w - mean) * rstd * gm.w + bt.w);
        size_t m_ = (size_t)(b * 4096 + hw);
        *(u16x4*)&xn[m_ * 512 + g * 16 + c4 * 4] = o;
    }
}

// ------------------------------------------------- weight prep: W^T as bf16
__global__ __launch_bounds__(256) void wprep(
    const float* __restrict__ Wq, const float* __restrict__ Wk,
    const float* __restrict__ Wv, const float* __restrict__ Wp,
    unsigned short* __restrict__ wqkvt, unsigned short* __restrict__ wpt)
{
    int idx = blockIdx.x * 256 + threadIdx.x; // 1,048,576 total
    if (idx < 786432) {
        int n = idx >> 9, k = idx & 511;
        int j = n >> 9, nn = n & 511;
        const float* W = (j == 0) ? Wq : (j == 1) ? Wk : Wv;
        wqkvt[idx] = f2bf(W[k * 512 + nn]);
    } else {
        int i2 = idx - 786432;
        int n = i2 >> 9, k = i2 & 511;
        wpt[i2] = f2bf(Wp[k * 512 + n]);
    }
}

// ------------------------------------------------------------- bf16 GEMM
template <int MODE>
__global__ __launch_bounds__(256) void gemm_kernel(
    const unsigned short* __restrict__ A, const unsigned short* __restrict__ Bt,
    const float* __restrict__ bias_q, const float* __restrict__ bias_k,
    const float* __restrict__ bias_v, const float* __restrict__ bias_p,
    const float* __restrict__ resid,
    unsigned short* __restrict__ Cbf, float* __restrict__ Cf)
{
    const int K = 512;
    int m0 = blockIdx.x * 128;
    int n0 = blockIdx.y * 128;
    int t = threadIdx.x;
    int l = t & 63, w = t >> 6;
    int wm = w >> 1, wn = w & 1;
    int lr = l & 15, lg = l >> 4;

    __shared__ unsigned short As[128][72];
    __shared__ unsigned short Bs[128][72];

    f32x4 acc[4][4];
    for (int i = 0; i < 4; ++i)
        for (int j = 0; j < 4; ++j) acc[i][j] = f32x4{0.f, 0.f, 0.f, 0.f};

    for (int k0 = 0; k0 < K; k0 += 64) {
        for (int c = 0; c < 4; ++c) {
            int flat = c * 256 + t;
            int row = flat >> 3, kc = (flat & 7) * 8;
            *(bf16x8*)&As[row][kc] = *(const bf16x8*)&A[(size_t)(m0 + row) * K + k0 + kc];
            *(bf16x8*)&Bs[row][kc] = *(const bf16x8*)&Bt[(size_t)(n0 + row) * K + k0 + kc];
        }
        __syncthreads();
        for (int ks = 0; ks < 2; ++ks) {
            bf16x8 af[4], bfr[4];
            for (int mi = 0; mi < 4; ++mi)
                af[mi] = *(bf16x8*)&As[wm * 64 + mi * 16 + lr][ks * 32 + lg * 8];
            for (int ni = 0; ni < 4; ++ni)
                bfr[ni] = *(bf16x8*)&Bs[wn * 64 + ni * 16 + lr][ks * 32 + lg * 8];
            for (int mi = 0; mi < 4; ++mi)
                for (int ni = 0; ni < 4; ++ni)
                    acc[mi][ni] = MFMA16(af[mi], bfr[ni], acc[mi][ni]);
        }
        __syncthreads();
    }

    for (int mi = 0; mi < 4; ++mi)
        for (int ni = 0; ni < 4; ++ni)
            for (int r = 0; r < 4; ++r) {
                int row = m0 + wm * 64 + mi * 16 + lg * 4 + r;
                int col = n0 + wn * 64 + ni * 16 + lr;
                float val = acc[mi][ni][r];
                if (MODE == 0) {
                    float bias, scl;
                    if (col < 512)       { bias = bias_q[col];        scl = SCALE; }
                    else if (col < 1024) { bias = bias_k[col - 512];  scl = SCALE; }
                    else                 { bias = bias_v[col - 1024]; scl = 1.0f;  }
                    Cbf[(size_t)row * 1536 + col] = f2bf((val + bias) * scl);
                } else {
                    Cf[(size_t)row * 512 + col] =
                        val + bias_p[col] + resid[(size_t)row * 512 + col];
                }
            }
}

// ------------------------------------------------ V transpose to [b][d][n]
__global__ __launch_bounds__(256) void vtrans(
    const unsigned short* __restrict__ qkv, unsigned short* __restrict__ vT)
{
    int n0 = blockIdx.x * 64, d0 = blockIdx.y * 64, b = blockIdx.z;
    int t = threadIdx.x;
    __shared__ unsigned short tile[64][72];
    for (int c = 0; c < 2; ++c) {
        int flat = c * 256 + t;
        int r = flat >> 3, cc = (flat & 7) * 8;
        *(bf16x8*)&tile[r][cc] =
            *(const bf16x8*)&qkv[(size_t)(b * 4096 + n0 + r) * 1536 + 1024 + d0 + cc];
    }
    __syncthreads();
    for (int c = 0; c < 2; ++c) {
        int flat = c * 256 + t;
        int dr = flat >> 3, nc = (flat & 7) * 8;
        bf16x8 v;
        for (int j = 0; j < 8; ++j) v[j] = (short)tile[nc + j][dr];
        *(bf16x8*)&vT[((size_t)b * 512 + d0 + dr) * 4096 + n0 + nc] = v;
    }
}

// ------------------------------------------------------------ QK^T + exp v2
// 128x256 tile, 512 thr (8 waves = 2m x 4n), grid (32,16,2). K=512, BK=64.
// 3-buffer 2-ahead staging with counted vmcnt(6): each stage's loads get a
// TWO-phase window before their consumer barrier (T3/T4).
__global__ __launch_bounds__(512) void qk_kernel(
    const unsigned short* __restrict__ qkv, unsigned short* __restrict__ P,
    float* __restrict__ lpart, int b0)
{
    int m0 = blockIdx.x * 128, n0 = blockIdx.y * 256, bb = blockIdx.z;
    int b = b0 + bb;
    int t = threadIdx.x, l = t & 63, w = t >> 6;
    int wm = w >> 2, wn = w & 3;
    int lr = l & 15, lg = l >> 4;

    __shared__ __align__(16) unsigned short lds[73728];  // 144 KB
    unsigned short* As = lds;           // 3 x 8192  (128 x 64)
    unsigned short* Bs = lds + 24576;   // 3 x 16384 (256 x 64)

    const unsigned short* A_ = qkv + (size_t)(b * 4096 + m0) * 1536;        // q
    const unsigned short* B_ = qkv + (size_t)(b * 4096 + n0) * 1536 + 512;  // k

    auto stage = [&](int s, int buf) {   // 6 vmem instr per wave
        int k0 = s * 64;
        unsigned short* ad = As + buf * 8192;
        unsigned short* bd = Bs + buf * 16384;
#pragma unroll
        for (int c = 0; c < 2; ++c) {
            int flat = c * 512 + t;
            int row = flat >> 3, u = flat & 7;
            g2l16(A_ + (size_t)row * 1536 + k0 + ((u ^ (row & 7)) << 3),
                  ad + (flat << 3));
        }
#pragma unroll
        for (int c = 0; c < 4; ++c) {
            int flat = c * 512 + t;
            int row = flat >> 3, u = flat & 7;
            g2l16(B_ + (size_t)row * 1536 + k0 + ((u ^ (row & 7)) << 3),
                  bd + (flat << 3));
        }
    };

    f32x4 acc[4][4];
#pragma unroll
    for (int i = 0; i < 4; ++i)
#pragma unroll
        for (int j = 0; j < 4; ++j) acc[i][j] = f32x4{0.f, 0.f, 0.f, 0.f};

    stage(0, 0);
    stage(1, 1);
    asm volatile("s_waitcnt vmcnt(6)" ::: "memory");   // stage(0) landed
    __builtin_amdgcn_s_barrier();
    __builtin_amdgcn_sched_barrier(0);

    for (int s = 0; s < 8; ++s) {
        if (s + 2 < 8) stage(s + 2, (s + 2) % 3);
        const unsigned short* Al = As + (s % 3) * 8192;
        const unsigned short* Bl = Bs + (s % 3) * 16384;
        __builtin_amdgcn_s_setprio(1);
#pragma unroll
        for (int ks = 0; ks < 2; ++ks) {
            bf16x8 af[4], bfr[4];
#pragma unroll
            for (int mi = 0; mi < 4; ++mi) {
                int row = wm * 64 + mi * 16 + lr;
                af[mi] = *(const bf16x8*)&Al[(row * 8 + ((ks * 4 + lg) ^ (row & 7))) << 3];
            }
#pragma unroll
            for (int ni = 0; ni < 4; ++ni) {
                int row = wn * 64 + ni * 16 + lr;
                bfr[ni] = *(const bf16x8*)&Bl[(row * 8 + ((ks * 4 + lg) ^ (row & 7))) << 3];
            }
#pragma unroll
            for (int mi = 0; mi < 4; ++mi)
#pragma unroll
                for (int ni = 0; ni < 4; ++ni)
                    acc[mi][ni] = MFMA16(af[mi], bfr[ni], acc[mi][ni]);
        }
        __builtin_amdgcn_s_setprio(0);
        // counted wait: next tile's loads (issued LAST iteration) must be done;
        // the stage just issued (s+2) stays in flight across the barrier.
        if (s < 6) asm volatile("s_waitcnt vmcnt(6) lgkmcnt(0)" ::: "memory");
        else       asm volatile("s_waitcnt vmcnt(0) lgkmcnt(0)" ::: "memory");
        __builtin_amdgcn_s_barrier();
        __builtin_amdgcn_sched_barrier(0);
    }

    // ---- epilogue: exp, row partial sums, repack via LDS, coalesced store
    unsigned short* Pl = lds;  // 128 x 256 ushort = 64 KB (buffers are free)
#pragma unroll
    for (int mi = 0; mi < 4; ++mi)
#pragma unroll
        for (int r = 0; r < 4; ++r) {
            float p[4];
            float srow = 0.f;
#pragma unroll
            for (int ni = 0; ni < 4; ++ni) {
                p[ni] = __expf(acc[mi][ni][r]);
                srow += p[ni];
            }
            srow += __shfl_xor(srow, 1); srow += __shfl_xor(srow, 2);
            srow += __shfl_xor(srow, 4); srow += __shfl_xor(srow, 8);
            int row = wm * 64 + mi * 16 + lg * 4 + r;
            if (lr == 0)
                lpart[(size_t)(bb * 64 + blockIdx.y * 4 + wn) * 4096 + m0 + row] = srow;
#pragma unroll
            for (int ni = 0; ni < 4; ++ni)
                Pl[row * 256 + wn * 64 + ni * 16 + lr] = f2bf(p[ni]);
        }
    __syncthreads();
#pragma unroll
    for (int c = 0; c < 8; ++c) {
        int flat = c * 512 + t;
        int row = flat >> 5, u = flat & 31;
        *(bf16x8*)&P[((size_t)(bb * 4096 + m0 + row)) * 4096 + n0 + u * 8] =
            *(const bf16x8*)&Pl[row * 256 + u * 8];
    }
}

// ----------------------------------------------------- l reduce (64 slices)
__global__ __launch_bounds__(256) void lred_kernel(
    const float* __restrict__ lpart, float* __restrict__ lsum)
{
    int rr = blockIdx.x * 256 + threadIdx.x;  // 0..8191
    int bb = rr >> 12, r = rr & 4095;
    float s = 0.f;
#pragma unroll
    for (int sl = 0; sl < 64; ++sl)
        s += lpart[(size_t)(bb * 64 + sl) * 4096 + r];
    lsum[rr] = 1.0f / s;
}

// ------------------------------------------------------------ PV GEMM v2
// O[q][d] = (P . V) / l. 128x128 tile, 512 thr (8 waves = 2m x 4n of 64x32),
// grid (32,4,2) = 256 blocks = 1/CU. K=4096, BK=64 (64 steps).
// 3-buffer 2-ahead staging, counted vmcnt(4).
__global__ __launch_bounds__(512) void pv_kernel(
    const unsigned short* __restrict__ P, const unsigned short* __restrict__ vT,
    const float* __restrict__ linv, unsigned short* __restrict__ outb, int b0)
{
    int m0 = blockIdx.x * 128, n0 = blockIdx.y * 128, bb = blockIdx.z;
    int b = b0 + bb;
    int t = threadIdx.x, l = t & 63, w = t >> 6;
    int wm = w >> 2, wn = w & 3;
    int lr = l & 15, lg = l >> 4;

    __shared__ __align__(16) unsigned short lds[49152];  // 96 KB
    unsigned short* As = lds;           // 3 x 8192 (128 x 64)
    unsigned short* Bs = lds + 24576;   // 3 x 8192 (128 x 64)

    const unsigned short* A_ = P + (size_t)(bb * 4096 + m0) * 4096;
    const unsigned short* B_ = vT + ((size_t)b * 512 + n0) * 4096;

    auto stage = [&](int s, int buf) {   // 4 vmem instr per wave
        int k0 = s * 64;
        unsigned short* ad = As + buf * 8192;
        unsigned short* bd = Bs + buf * 8192;
#pragma unroll
        for (int c = 0; c < 2; ++c) {
            int flat = c * 512 + t;
            int row = flat >> 3, u = flat & 7;
            g2l16(A_ + (size_t)row * 4096 + k0 + ((u ^ (row & 7)) << 3),
                  ad + (flat << 3));
        }
#pragma unroll
        for (int c = 0; c < 2; ++c) {
            int flat = c * 512 + t;
            int row = flat >> 3, u = flat & 7;
            g2l16(B_ + (size_t)row * 4096 + k0 + ((u ^ (row & 7)) << 3),
                  bd + (flat << 3));
        }
    };

    f32x4 acc[4][2];
#pragma unroll
    for (int i = 0; i < 4; ++i)
#pragma unroll
        for (int j = 0; j < 2; ++j) acc[i][j] = f32x4{0.f, 0.f, 0.f, 0.f};

    stage(0, 0);
    stage(1, 1);
    asm volatile("s_waitcnt vmcnt(4)" ::: "memory");
    __builtin_amdgcn_s_barrier();
    __builtin_amdgcn_sched_barrier(0);

    for (int s = 0; s < 64; ++s) {
        if (s + 2 < 64) stage(s + 2, (s + 2) % 3);
        const unsigned short* Al = As + (s % 3) * 8192;
        const unsigned short* Bl = Bs + (s % 3) * 8192;
        __builtin_amdgcn_s_setprio(1);
#pragma unroll
        for (int ks = 0; ks < 2; ++ks) {
            bf16x8 af[4], bfr[2];
#pragma unroll
            for (int mi = 0; mi < 4; ++mi) {
                int row = wm * 64 + mi * 16 + lr;
                af[mi] = *(const bf16x8*)&Al[(row * 8 + ((ks * 4 + lg) ^ (row & 7))) << 3];
            }
#pragma unroll
            for (int ni = 0; ni < 2; ++ni) {
                int row = wn * 32 + ni * 16 + lr;
                bfr[ni] = *(const bf16x8*)&Bl[(row * 8 + ((ks * 4 + lg) ^ (row & 7))) << 3];
            }
#pragma unroll
            for (int mi = 0; mi < 4; ++mi)
#pragma unroll
                for (int ni = 0; ni < 2; ++ni)
                    acc[mi][ni] = MFMA16(af[mi], bfr[ni], acc[mi][ni]);
        }
        __builtin_amdgcn_s_setprio(0);
        if (s < 62) asm volatile("s_waitcnt vmcnt(4) lgkmcnt(0)" ::: "memory");
        else        asm volatile("s_waitcnt vmcnt(0) lgkmcnt(0)" ::: "memory");
        __builtin_amdgcn_s_barrier();
        __builtin_amdgcn_sched_barrier(0);
    }

#pragma unroll
    for (int mi = 0; mi < 4; ++mi)
#pragma unroll
        for (int r = 0; r < 4; ++r) {
            int row = m0 + wm * 64 + mi * 16 + lg * 4 + r;
            float inv = linv[bb * 4096 + row];
#pragma unroll
            for (int ni = 0; ni < 2; ++ni) {
                int col = n0 + wn * 32 + ni * 16 + lr;
                outb[(size_t)(b * 4096 + row) * 512 + col] =
                    f2bf(acc[mi][ni][r] * inv);
            }
        }
}

// --------------------------------------------------------------- launcher
extern "C" void kernel_launch(void* const* d_in, const int* in_sizes, int n_in,
                              void* d_out, int out_size, void* d_ws, size_t ws_size,
                              hipStream_t stream)
{
    const float* x     = (const float*)d_in[0];
    const float* gamma = (const float*)d_in[1];
    const float* beta  = (const float*)d_in[2];
    const float* Wq = (const float*)d_in[3];
    const float* bq = (const float*)d_in[4];
    const float* Wk = (const float*)d_in[5];
    const float* bk = (const float*)d_in[6];
    const float* Wv = (const float*)d_in[7];
    const float* bv = (const float*)d_in[8];
    const float* Wp = (const float*)d_in[9];
    const float* bp = (const float*)d_in[10];
    float* out = (float*)d_out;

    unsigned short* xn    = (unsigned short*)d_ws;                 // 16384*512 (reused as attn out)
    unsigned short* wqkvt = xn + (size_t)16384 * 512;              // 1536*512
    unsigned short* wpt   = wqkvt + (size_t)1536 * 512;            // 512*512
    unsigned short* qkv   = wpt + (size_t)512 * 512;               // 16384*1536
    unsigned short* vT    = qkv + (size_t)16384 * 1536;            // 4*512*4096
    unsigned short* P     = vT + (size_t)4 * 512 * 4096;           // 2*4096*4096 (64MB)
    float* lpart = (float*)(P + (size_t)2 * 4096 * 4096);          // 128*4096 f32
    float* linv  = lpart + (size_t)128 * 4096;                     // 8192 f32

    gn_kernel<<<dim3(128), dim3(256), 0, stream>>>(x, gamma, beta, xn);
    wprep<<<dim3(4096), dim3(256), 0, stream>>>(Wq, Wk, Wv, Wp, wqkvt, wpt);
    gemm_kernel<0><<<dim3(128, 12), dim3(256), 0, stream>>>(
        xn, wqkvt, bq, bk, bv, nullptr, nullptr, qkv, nullptr);
    vtrans<<<dim3(64, 8, 4), dim3(256), 0, stream>>>(qkv, vT);

    for (int b0 = 0; b0 < 4; b0 += 2) {
        qk_kernel<<<dim3(32, 16, 2), dim3(512), 0, stream>>>(qkv, P, lpart, b0);
        lred_kernel<<<dim3(32), dim3(256), 0, stream>>>(lpart, linv);
        pv_kernel<<<dim3(32, 4, 2), dim3(512), 0, stream>>>(P, vT, linv, xn, b0);
    }

    gemm_kernel<1><<<dim3(128, 4), dim3(256), 0, stream>>>(
        xn, wpt, nullptr, nullptr, nullptr, bp, x, nullptr, out);
}

// Round 10
// 302.767 us; speedup vs baseline: 1.6376x; 1.1703x over previous
//
#include <hip/hip_runtime.h>
#include <hip/hip_bf16.h>

typedef __attribute__((ext_vector_type(8))) short bf16x8;
typedef __attribute__((ext_vector_type(4))) float f32x4;
typedef __attribute__((ext_vector_type(4))) unsigned short u16x4;

#define MFMA16(a, b, c) __builtin_amdgcn_mfma_f32_16x16x32_bf16(a, b, c, 0, 0, 0)

#define SCALE 0.21022410381342865f /* 512^(-1/4) */

__device__ __forceinline__ unsigned short f2bf(float f) {
    union { float f; unsigned u; } v; v.f = f;
    unsigned r = v.u + 0x7FFF + ((v.u >> 16) & 1);
    return (unsigned short)(r >> 16);
}

typedef __attribute__((address_space(3))) void lds_void;
typedef const __attribute__((address_space(1))) void gbl_void;
__device__ __forceinline__ void g2l16(const void* g, void* l) {
    __builtin_amdgcn_global_load_lds((gbl_void*)g, (lds_void*)l, 16, 0, 0);
}

#define PHASE_BARRIER() do { \
    asm volatile("s_waitcnt vmcnt(0) lgkmcnt(0)" ::: "memory"); \
    __builtin_amdgcn_s_barrier(); \
    __builtin_amdgcn_sched_barrier(0); \
} while (0)

// ---------------------------------------------------------------- GroupNorm
__global__ __launch_bounds__(256) void gn_kernel(
    const float* __restrict__ x, const float* __restrict__ gamma,
    const float* __restrict__ beta, unsigned short* __restrict__ xn)
{
    int b = blockIdx.x >> 5, g = blockIdx.x & 31;
    int t = threadIdx.x;
    const float4* xf4 = (const float4*)x;
    size_t base4 = (size_t)b * (4096 * 128) + g * 4;

    float s = 0.f, ss = 0.f;
    for (int i = 0; i < 64; ++i) {
        int flat = i * 256 + t;
        int hw = flat >> 2, c4 = flat & 3;
        float4 v = xf4[base4 + (size_t)hw * 128 + c4];
        s  += v.x + v.y + v.z + v.w;
        ss += v.x * v.x + v.y * v.y + v.z * v.z + v.w * v.w;
    }
    for (int m = 32; m >= 1; m >>= 1) { s += __shfl_xor(s, m); ss += __shfl_xor(ss, m); }
    __shared__ float rs_[4], rss_[4];
    int wv = t >> 6;
    if ((t & 63) == 0) { rs_[wv] = s; rss_[wv] = ss; }
    __syncthreads();
    float tot  = rs_[0] + rs_[1] + rs_[2] + rs_[3];
    float tot2 = rss_[0] + rss_[1] + rss_[2] + rss_[3];
    float mean = tot * (1.f / 65536.f);
    float var  = tot2 * (1.f / 65536.f) - mean * mean;
    float rstd = rsqrtf(var + 1e-6f);

    const float4* g4 = (const float4*)gamma;
    const float4* b4 = (const float4*)beta;
    for (int i = 0; i < 64; ++i) {
        int flat = i * 256 + t;
        int hw = flat >> 2, c4 = flat & 3;
        float4 v  = xf4[base4 + (size_t)hw * 128 + c4];
        float4 gm = g4[g * 4 + c4], bt = b4[g * 4 + c4];
        u16x4 o;
        o.x = f2bf((v.x - mean) * rstd * gm.x + bt.x);
        o.y = f2bf((v.y - mean) * rstd * gm.y + bt.y);
        o.z = f2bf((v.z - mean) * rstd * gm.z + bt.z);
        o.w = f2bf((v.w - mean) * rstd * gm.w + bt.w);
        size_t m_ = (size_t)(b * 4096 + hw);
        *(u16x4*)&xn[m_ * 512 + g * 16 + c4 * 4] = o;
    }
}

// ------------------------------------------------- weight prep: W^T as bf16
__global__ __launch_bounds__(256) void wprep(
    const float* __restrict__ Wq, const float* __restrict__ Wk,
    const float* __restrict__ Wv, const float* __restrict__ Wp,
    unsigned short* __restrict__ wqkvt, unsigned short* __restrict__ wpt)
{
    int idx = blockIdx.x * 256 + threadIdx.x; // 1,048,576 total
    if (idx < 786432) {
        int n = idx >> 9, k = idx & 511;
        int j = n >> 9, nn = n & 511;
        const float* W = (j == 0) ? Wq : (j == 1) ? Wk : Wv;
        wqkvt[idx] = f2bf(W[k * 512 + nn]);
    } else {
        int i2 = idx - 786432;
        int n = i2 >> 9, k = i2 & 511;
        wpt[i2] = f2bf(Wp[k * 512 + n]);
    }
}

// ------------------------------------------------------------- bf16 GEMM
template <int MODE>
__global__ __launch_bounds__(256) void gemm_kernel(
    const unsigned short* __restrict__ A, const unsigned short* __restrict__ Bt,
    const float* __restrict__ bias_q, const float* __restrict__ bias_k,
    const float* __restrict__ bias_v, const float* __restrict__ bias_p,
    const float* __restrict__ resid,
    unsigned short* __restrict__ Cbf, float* __restrict__ Cf)
{
    const int K = 512;
    int m0 = blockIdx.x * 128;
    int n0 = blockIdx.y * 128;
    int t = threadIdx.x;
    int l = t & 63, w = t >> 6;
    int wm = w >> 1, wn = w & 1;
    int lr = l & 15, lg = l >> 4;

    __shared__ unsigned short As[128][72];
    __shared__ unsigned short Bs[128][72];

    f32x4 acc[4][4];
    for (int i = 0; i < 4; ++i)
        for (int j = 0; j < 4; ++j) acc[i][j] = f32x4{0.f, 0.f, 0.f, 0.f};

    for (int k0 = 0; k0 < K; k0 += 64) {
        for (int c = 0; c < 4; ++c) {
            int flat = c * 256 + t;
            int row = flat >> 3, kc = (flat & 7) * 8;
            *(bf16x8*)&As[row][kc] = *(const bf16x8*)&A[(size_t)(m0 + row) * K + k0 + kc];
            *(bf16x8*)&Bs[row][kc] = *(const bf16x8*)&Bt[(size_t)(n0 + row) * K + k0 + kc];
        }
        __syncthreads();
        for (int ks = 0; ks < 2; ++ks) {
            bf16x8 af[4], bfr[4];
            for (int mi = 0; mi < 4; ++mi)
                af[mi] = *(bf16x8*)&As[wm * 64 + mi * 16 + lr][ks * 32 + lg * 8];
            for (int ni = 0; ni < 4; ++ni)
                bfr[ni] = *(bf16x8*)&Bs[wn * 64 + ni * 16 + lr][ks * 32 + lg * 8];
            for (int mi = 0; mi < 4; ++mi)
                for (int ni = 0; ni < 4; ++ni)
                    acc[mi][ni] = MFMA16(af[mi], bfr[ni], acc[mi][ni]);
        }
        __syncthreads();
    }

    for (int mi = 0; mi < 4; ++mi)
        for (int ni = 0; ni < 4; ++ni)
            for (int r = 0; r < 4; ++r) {
                int row = m0 + wm * 64 + mi * 16 + lg * 4 + r;
                int col = n0 + wn * 64 + ni * 16 + lr;
                float val = acc[mi][ni][r];
                if (MODE == 0) {
                    float bias, scl;
                    if (col < 512)       { bias = bias_q[col];        scl = SCALE; }
                    else if (col < 1024) { bias = bias_k[col - 512];  scl = SCALE; }
                    else                 { bias = bias_v[col - 1024]; scl = 1.0f;  }
                    Cbf[(size_t)row * 1536 + col] = f2bf((val + bias) * scl);
                } else {
                    Cf[(size_t)row * 512 + col] =
                        val + bias_p[col] + resid[(size_t)row * 512 + col];
                }
            }
}

// ------------------------------------------------ V transpose to [b][d][n]
__global__ __launch_bounds__(256) void vtrans(
    const unsigned short* __restrict__ qkv, unsigned short* __restrict__ vT)
{
    int n0 = blockIdx.x * 64, d0 = blockIdx.y * 64, b = blockIdx.z;
    int t = threadIdx.x;
    __shared__ unsigned short tile[64][72];
    for (int c = 0; c < 2; ++c) {
        int flat = c * 256 + t;
        int r = flat >> 3, cc = (flat & 7) * 8;
        *(bf16x8*)&tile[r][cc] =
            *(const bf16x8*)&qkv[(size_t)(b * 4096 + n0 + r) * 1536 + 1024 + d0 + cc];
    }
    __syncthreads();
    for (int c = 0; c < 2; ++c) {
        int flat = c * 256 + t;
        int dr = flat >> 3, nc = (flat & 7) * 8;
        bf16x8 v;
        for (int j = 0; j < 8; ++j) v[j] = (short)tile[nc + j][dr];
        *(bf16x8*)&vT[((size_t)b * 512 + d0 + dr) * 4096 + n0 + nc] = v;
    }
}

// ------------------------------------------------------------ QK^T + exp v3
// 256x256 tile, 512 thr (8 waves = 2m x 4n, each 128x64), BK=64, 2-buffer.
// Grid 512 1-D blocks, XCD-aware decode: xcd=W&7 -> bb=xcd>>2,
// nb=(xcd&3)*4+(i&3), mb=i>>2 (bijective) -> K-panels L2-resident per XCD.
// One stage per step issued BEFORE compute (~2000-cyc window >> latency),
// single vmcnt(0)+barrier per step. Epilogue: exp + block row-sums (one
// lpart slice per n-block) + 128 KB LDS repack -> coalesced 512B-row stores.
__global__ __launch_bounds__(512) void qk_kernel(
    const unsigned short* __restrict__ qkv, unsigned short* __restrict__ P,
    float* __restrict__ lpart, int b0)
{
    int W = blockIdx.x;
    int xcd = W & 7, i = W >> 3;
    int bb = xcd >> 2;
    int nb = (xcd & 3) * 4 + (i & 3);
    int mb = i >> 2;
    int m0 = mb * 256, n0 = nb * 256;
    int b = b0 + bb;

    int t = threadIdx.x, l = t & 63, w = t >> 6;
    int wm = w >> 2, wn = w & 3;
    int lr = l & 15, lg = l >> 4;

    __shared__ __align__(16) unsigned short lds[67584];  // 132 KB
    // A buf0 [0,16384), A buf1 [16384,32768), B buf0 [32768,49152), B buf1 [49152,65536)
    float* Lw = (float*)(lds + 65536);                    // 4 x 256 f32

    const unsigned short* A_ = qkv + (size_t)(b * 4096 + m0) * 1536;        // q
    const unsigned short* B_ = qkv + (size_t)(b * 4096 + n0) * 1536 + 512;  // k

    auto stage = [&](int s, int buf) {   // 8 vmem instr per thread
        int k0 = s * 64;
        unsigned short* ad = lds + buf * 16384;
        unsigned short* bd = lds + 32768 + buf * 16384;
#pragma unroll
        for (int c = 0; c < 4; ++c) {
            int flat = c * 512 + t;              // 2048 slots: 256 rows x 8 units
            int row = flat >> 3, u = flat & 7;
            g2l16(A_ + (size_t)row * 1536 + k0 + ((u ^ (row & 7)) << 3),
                  ad + (flat << 3));
        }
#pragma unroll
        for (int c = 0; c < 4; ++c) {
            int flat = c * 512 + t;
            int row = flat >> 3, u = flat & 7;
            g2l16(B_ + (size_t)row * 1536 + k0 + ((u ^ (row & 7)) << 3),
                  bd + (flat << 3));
        }
    };

    f32x4 acc[8][4];
#pragma unroll
    for (int mi = 0; mi < 8; ++mi)
#pragma unroll
        for (int ni = 0; ni < 4; ++ni) acc[mi][ni] = f32x4{0.f, 0.f, 0.f, 0.f};

    stage(0, 0);
    PHASE_BARRIER();

    for (int s = 0; s < 8; ++s) {
        if (s + 1 < 8) stage(s + 1, (s + 1) & 1);
        const unsigned short* Al = lds + (s & 1) * 16384;
        const unsigned short* Bl = lds + 32768 + (s & 1) * 16384;
        __builtin_amdgcn_s_setprio(1);
#pragma unroll
        for (int ks = 0; ks < 2; ++ks) {
            bf16x8 af[8], bfr[4];
#pragma unroll
            for (int mi = 0; mi < 8; ++mi) {
                int row = wm * 128 + mi * 16 + lr;
                af[mi] = *(const bf16x8*)&Al[(row * 8 + ((ks * 4 + lg) ^ (row & 7))) << 3];
            }
#pragma unroll
            for (int ni = 0; ni < 4; ++ni) {
                int row = wn * 64 + ni * 16 + lr;
                bfr[ni] = *(const bf16x8*)&Bl[(row * 8 + ((ks * 4 + lg) ^ (row & 7))) << 3];
            }
#pragma unroll
            for (int mi = 0; mi < 8; ++mi)
#pragma unroll
                for (int ni = 0; ni < 4; ++ni)
                    acc[mi][ni] = MFMA16(af[mi], bfr[ni], acc[mi][ni]);
        }
        __builtin_amdgcn_s_setprio(0);
        PHASE_BARRIER();
    }

    // ---- epilogue: exp, wave row-sum partials, repack P in LDS
    unsigned short* Pl = lds;            // 256 x 256 ushort = 128 KB
#pragma unroll
    for (int mi = 0; mi < 8; ++mi)
#pragma unroll
        for (int r = 0; r < 4; ++r) {
            float p[4];
            float srow = 0.f;
#pragma unroll
            for (int ni = 0; ni < 4; ++ni) {
                p[ni] = __expf(acc[mi][ni][r]);
                srow += p[ni];
            }
            srow += __shfl_xor(srow, 1); srow += __shfl_xor(srow, 2);
            srow += __shfl_xor(srow, 4); srow += __shfl_xor(srow, 8);
            int row = wm * 128 + mi * 16 + lg * 4 + r;
            if (lr == 0) Lw[wn * 256 + row] = srow;
#pragma unroll
            for (int ni = 0; ni < 4; ++ni)
                Pl[row * 256 + wn * 64 + ni * 16 + lr] = f2bf(p[ni]);
        }
    __syncthreads();

    // row sums across the 4 n-waves -> this block's lpart slice
    if (t < 256)
        lpart[(size_t)(bb * 16 + nb) * 4096 + m0 + t] =
            Lw[t] + Lw[256 + t] + Lw[512 + t] + Lw[768 + t];

    // coalesced P store (512B rows)
#pragma unroll
    for (int c = 0; c < 16; ++c) {
        int flat = c * 512 + t;              // 8192 slots: 256 rows x 32 units
        int row = flat >> 5, u = flat & 31;
        *(bf16x8*)&P[((size_t)(bb * 4096 + m0 + row)) * 4096 + n0 + u * 8] =
            *(const bf16x8*)&Pl[row * 256 + u * 8];
    }
}

// ----------------------------------------------------- l reduce (16 slices)
__global__ __launch_bounds__(256) void lred_kernel(
    const float* __restrict__ lpart, float* __restrict__ lsum)
{
    int rr = blockIdx.x * 256 + threadIdx.x;  // 0..8191
    int bb = rr >> 12, r = rr & 4095;
    float s = 0.f;
#pragma unroll
    for (int sl = 0; sl < 16; ++sl)
        s += lpart[(size_t)(bb * 16 + sl) * 4096 + r];
    lsum[rr] = 1.0f / s;
}

// ------------------------------------------------------------ PV GEMM v2
// O[q][d] = (P . V) / l. 128x128 tile, 512 thr (8 waves = 2m x 4n of 64x32),
// grid (32,4,2) = 256 blocks = 1/CU. K=4096, BK=64 (64 steps).
// 3-buffer 2-ahead staging, counted vmcnt(4).
__global__ __launch_bounds__(512) void pv_kernel(
    const unsigned short* __restrict__ P, const unsigned short* __restrict__ vT,
    const float* __restrict__ linv, unsigned short* __restrict__ outb, int b0)
{
    int m0 = blockIdx.x * 128, n0 = blockIdx.y * 128, bb = blockIdx.z;
    int b = b0 + bb;
    int t = threadIdx.x, l = t & 63, w = t >> 6;
    int wm = w >> 2, wn = w & 3;
    int lr = l & 15, lg = l >> 4;

    __shared__ __align__(16) unsigned short lds[49152];  // 96 KB
    unsigned short* As = lds;           // 3 x 8192 (128 x 64)
    unsigned short* Bs = lds + 24576;   // 3 x 8192 (128 x 64)

    const unsigned short* A_ = P + (size_t)(bb * 4096 + m0) * 4096;
    const unsigned short* B_ = vT + ((size_t)b * 512 + n0) * 4096;

    auto stage = [&](int s, int buf) {   // 4 vmem instr per wave
        int k0 = s * 64;
        unsigned short* ad = As + buf * 8192;
        unsigned short* bd = Bs + buf * 8192;
#pragma unroll
        for (int c = 0; c < 2; ++c) {
            int flat = c * 512 + t;
            int row = flat >> 3, u = flat & 7;
            g2l16(A_ + (size_t)row * 4096 + k0 + ((u ^ (row & 7)) << 3),
                  ad + (flat << 3));
        }
#pragma unroll
        for (int c = 0; c < 2; ++c) {
            int flat = c * 512 + t;
            int row = flat >> 3, u = flat & 7;
            g2l16(B_ + (size_t)row * 4096 + k0 + ((u ^ (row & 7)) << 3),
                  bd + (flat << 3));
        }
    };

    f32x4 acc[4][2];
#pragma unroll
    for (int i = 0; i < 4; ++i)
#pragma unroll
        for (int j = 0; j < 2; ++j) acc[i][j] = f32x4{0.f, 0.f, 0.f, 0.f};

    stage(0, 0);
    stage(1, 1);
    asm volatile("s_waitcnt vmcnt(4)" ::: "memory");
    __builtin_amdgcn_s_barrier();
    __builtin_amdgcn_sched_barrier(0);

    for (int s = 0; s < 64; ++s) {
        if (s + 2 < 64) stage(s + 2, (s + 2) % 3);
        const unsigned short* Al = As + (s % 3) * 8192;
        const unsigned short* Bl = Bs + (s % 3) * 8192;
        __builtin_amdgcn_s_setprio(1);
#pragma unroll
        for (int ks = 0; ks < 2; ++ks) {
            bf16x8 af[4], bfr[2];
#pragma unroll
            for (int mi = 0; mi < 4; ++mi) {
                int row = wm * 64 + mi * 16 + lr;
                af[mi] = *(const bf16x8*)&Al[(row * 8 + ((ks * 4 + lg) ^ (row & 7))) << 3];
            }
#pragma unroll
            for (int ni = 0; ni < 2; ++ni) {
                int row = wn * 32 + ni * 16 + lr;
                bfr[ni] = *(const bf16x8*)&Bl[(row * 8 + ((ks * 4 + lg) ^ (row & 7))) << 3];
            }
#pragma unroll
            for (int mi = 0; mi < 4; ++mi)
#pragma unroll
                for (int ni = 0; ni < 2; ++ni)
                    acc[mi][ni] = MFMA16(af[mi], bfr[ni], acc[mi][ni]);
        }
        __builtin_amdgcn_s_setprio(0);
        if (s < 62) asm volatile("s_waitcnt vmcnt(4) lgkmcnt(0)" ::: "memory");
        else        asm volatile("s_waitcnt vmcnt(0) lgkmcnt(0)" ::: "memory");
        __builtin_amdgcn_s_barrier();
        __builtin_amdgcn_sched_barrier(0);
    }

#pragma unroll
    for (int mi = 0; mi < 4; ++mi)
#pragma unroll
        for (int r = 0; r < 4; ++r) {
            int row = m0 + wm * 64 + mi * 16 + lg * 4 + r;
            float inv = linv[bb * 4096 + row];
#pragma unroll
            for (int ni = 0; ni < 2; ++ni) {
                int col = n0 + wn * 32 + ni * 16 + lr;
                outb[(size_t)(b * 4096 + row) * 512 + col] =
                    f2bf(acc[mi][ni][r] * inv);
            }
        }
}

// --------------------------------------------------------------- launcher
extern "C" void kernel_launch(void* const* d_in, const int* in_sizes, int n_in,
                              void* d_out, int out_size, void* d_ws, size_t ws_size,
                              hipStream_t stream)
{
    const float* x     = (const float*)d_in[0];
    const float* gamma = (const float*)d_in[1];
    const float* beta  = (const float*)d_in[2];
    const float* Wq = (const float*)d_in[3];
    const float* bq = (const float*)d_in[4];
    const float* Wk = (const float*)d_in[5];
    const float* bk = (const float*)d_in[6];
    const float* Wv = (const float*)d_in[7];
    const float* bv = (const float*)d_in[8];
    const float* Wp = (const float*)d_in[9];
    const float* bp = (const float*)d_in[10];
    float* out = (float*)d_out;

    unsigned short* xn    = (unsigned short*)d_ws;                 // 16384*512 (reused as attn out)
    unsigned short* wqkvt = xn + (size_t)16384 * 512;              // 1536*512
    unsigned short* wpt   = wqkvt + (size_t)1536 * 512;            // 512*512
    unsigned short* qkv   = wpt + (size_t)512 * 512;               // 16384*1536
    unsigned short* vT    = qkv + (size_t)16384 * 1536;            // 4*512*4096
    unsigned short* P     = vT + (size_t)4 * 512 * 4096;           // 2*4096*4096 (64MB)
    float* lpart = (float*)(P + (size_t)2 * 4096 * 4096);          // 32*4096 f32
    float* linv  = lpart + (size_t)128 * 4096;                     // 8192 f32

    gn_kernel<<<dim3(128), dim3(256), 0, stream>>>(x, gamma, beta, xn);
    wprep<<<dim3(4096), dim3(256), 0, stream>>>(Wq, Wk, Wv, Wp, wqkvt, wpt);
    gemm_kernel<0><<<dim3(128, 12), dim3(256), 0, stream>>>(
        xn, wqkvt, bq, bk, bv, nullptr, nullptr, qkv, nullptr);
    vtrans<<<dim3(64, 8, 4), dim3(256), 0, stream>>>(qkv, vT);

    for (int b0 = 0; b0 < 4; b0 += 2) {
        qk_kernel<<<dim3(512), dim3(512), 0, stream>>>(qkv, P, lpart, b0);
        lred_kernel<<<dim3(32), dim3(256), 0, stream>>>(lpart, linv);
        pv_kernel<<<dim3(32, 4, 2), dim3(512), 0, stream>>>(P, vT, linv, xn, b0);
    }

    gemm_kernel<1><<<dim3(128, 4), dim3(256), 0, stream>>>(
        xn, wpt, nullptr, nullptr, nullptr, bp, x, nullptr, out);
}

// Round 11
// 284.280 us; speedup vs baseline: 1.7441x; 1.0650x over previous
//
#include <hip/hip_runtime.h>
#include <hip/hip_bf16.h>

typedef __attribute__((ext_vector_type(8))) short bf16x8;
typedef __attribute__((ext_vector_type(4))) float f32x4;
typedef __attribute__((ext_vector_type(4))) unsigned short u16x4;

#define MFMA16(a, b, c) __builtin_amdgcn_mfma_f32_16x16x32_bf16(a, b, c, 0, 0, 0)

#define SCALE 0.21022410381342865f /* 512^(-1/4) */

__device__ __forceinline__ unsigned short f2bf(float f) {
    union { float f; unsigned u; } v; v.f = f;
    unsigned r = v.u + 0x7FFF + ((v.u >> 16) & 1);
    return (unsigned short)(r >> 16);
}

__device__ __forceinline__ unsigned cvtpk(float lo, float hi) {
    unsigned r;
    asm("v_cvt_pk_bf16_f32 %0, %1, %2" : "=v"(r) : "v"(lo), "v"(hi));
    return r;
}

typedef __attribute__((address_space(3))) void lds_void;
typedef const __attribute__((address_space(1))) void gbl_void;
__device__ __forceinline__ void g2l16(const void* g, void* l) {
    __builtin_amdgcn_global_load_lds((gbl_void*)g, (lds_void*)l, 16, 0, 0);
}

#define PHASE_BARRIER() do { \
    asm volatile("s_waitcnt vmcnt(0) lgkmcnt(0)" ::: "memory"); \
    __builtin_amdgcn_s_barrier(); \
    __builtin_amdgcn_sched_barrier(0); \
} while (0)

#define LGKM_BARRIER() do { \
    asm volatile("s_waitcnt lgkmcnt(0)" ::: "memory"); \
    __builtin_amdgcn_s_barrier(); \
    __builtin_amdgcn_sched_barrier(0); \
} while (0)

// ---------------------------------------------------------------- GroupNorm
__global__ __launch_bounds__(256) void gn_kernel(
    const float* __restrict__ x, const float* __restrict__ gamma,
    const float* __restrict__ beta, unsigned short* __restrict__ xn)
{
    int b = blockIdx.x >> 5, g = blockIdx.x & 31;
    int t = threadIdx.x;
    const float4* xf4 = (const float4*)x;
    size_t base4 = (size_t)b * (4096 * 128) + g * 4;

    float s = 0.f, ss = 0.f;
    for (int i = 0; i < 64; ++i) {
        int flat = i * 256 + t;
        int hw = flat >> 2, c4 = flat & 3;
        float4 v = xf4[base4 + (size_t)hw * 128 + c4];
        s  += v.x + v.y + v.z + v.w;
        ss += v.x * v.x + v.y * v.y + v.z * v.z + v.w * v.w;
    }
    for (int m = 32; m >= 1; m >>= 1) { s += __shfl_xor(s, m); ss += __shfl_xor(ss, m); }
    __shared__ float rs_[4], rss_[4];
    int wv = t >> 6;
    if ((t & 63) == 0) { rs_[wv] = s; rss_[wv] = ss; }
    __syncthreads();
    float tot  = rs_[0] + rs_[1] + rs_[2] + rs_[3];
    float tot2 = rss_[0] + rss_[1] + rss_[2] + rss_[3];
    float mean = tot * (1.f / 65536.f);
    float var  = tot2 * (1.f / 65536.f) - mean * mean;
    float rstd = rsqrtf(var + 1e-6f);

    const float4* g4 = (const float4*)gamma;
    const float4* b4 = (const float4*)beta;
    for (int i = 0; i < 64; ++i) {
        int flat = i * 256 + t;
        int hw = flat >> 2, c4 = flat & 3;
        float4 v  = xf4[base4 + (size_t)hw * 128 + c4];
        float4 gm = g4[g * 4 + c4], bt = b4[g * 4 + c4];
        u16x4 o;
        o.x = f2bf((v.x - mean) * rstd * gm.x + bt.x);
        o.y = f2bf((v.y - mean) * rstd * gm.y + bt.y);
        o.z = f2bf((v.z - mean) * rstd * gm.z + bt.z);
        o.w = f2bf((v.w - mean) * rstd * gm.w + bt.w);
        size_t m_ = (size_t)(b * 4096 + hw);
        *(u16x4*)&xn[m_ * 512 + g * 16 + c4 * 4] = o;
    }
}

// ------------------------------------------------- weight prep: W^T as bf16
__global__ __launch_bounds__(256) void wprep(
    const float* __restrict__ Wq, const float* __restrict__ Wk,
    const float* __restrict__ Wv, const float* __restrict__ Wp,
    unsigned short* __restrict__ wqkvt, unsigned short* __restrict__ wpt)
{
    int idx = blockIdx.x * 256 + threadIdx.x; // 1,048,576 total
    if (idx < 786432) {
        int n = idx >> 9, k = idx & 511;
        int j = n >> 9, nn = n & 511;
        const float* W = (j == 0) ? Wq : (j == 1) ? Wk : Wv;
        wqkvt[idx] = f2bf(W[k * 512 + nn]);
    } else {
        int i2 = idx - 786432;
        int n = i2 >> 9, k = i2 & 511;
        wpt[i2] = f2bf(Wp[k * 512 + n]);
    }
}

// ------------------------------------------------------------- bf16 GEMM
template <int MODE>
__global__ __launch_bounds__(256) void gemm_kernel(
    const unsigned short* __restrict__ A, const unsigned short* __restrict__ Bt,
    const float* __restrict__ bias_q, const float* __restrict__ bias_k,
    const float* __restrict__ bias_v, const float* __restrict__ bias_p,
    const float* __restrict__ resid,
    unsigned short* __restrict__ Cbf, float* __restrict__ Cf)
{
    const int K = 512;
    int m0 = blockIdx.x * 128;
    int n0 = blockIdx.y * 128;
    int t = threadIdx.x;
    int l = t & 63, w = t >> 6;
    int wm = w >> 1, wn = w & 1;
    int lr = l & 15, lg = l >> 4;

    __shared__ unsigned short As[128][72];
    __shared__ unsigned short Bs[128][72];

    f32x4 acc[4][4];
    for (int i = 0; i < 4; ++i)
        for (int j = 0; j < 4; ++j) acc[i][j] = f32x4{0.f, 0.f, 0.f, 0.f};

    for (int k0 = 0; k0 < K; k0 += 64) {
        for (int c = 0; c < 4; ++c) {
            int flat = c * 256 + t;
            int row = flat >> 3, kc = (flat & 7) * 8;
            *(bf16x8*)&As[row][kc] = *(const bf16x8*)&A[(size_t)(m0 + row) * K + k0 + kc];
            *(bf16x8*)&Bs[row][kc] = *(const bf16x8*)&Bt[(size_t)(n0 + row) * K + k0 + kc];
        }
        __syncthreads();
        for (int ks = 0; ks < 2; ++ks) {
            bf16x8 af[4], bfr[4];
            for (int mi = 0; mi < 4; ++mi)
                af[mi] = *(bf16x8*)&As[wm * 64 + mi * 16 + lr][ks * 32 + lg * 8];
            for (int ni = 0; ni < 4; ++ni)
                bfr[ni] = *(bf16x8*)&Bs[wn * 64 + ni * 16 + lr][ks * 32 + lg * 8];
            for (int mi = 0; mi < 4; ++mi)
                for (int ni = 0; ni < 4; ++ni)
                    acc[mi][ni] = MFMA16(af[mi], bfr[ni], acc[mi][ni]);
        }
        __syncthreads();
    }

    for (int mi = 0; mi < 4; ++mi)
        for (int ni = 0; ni < 4; ++ni)
            for (int r = 0; r < 4; ++r) {
                int row = m0 + wm * 64 + mi * 16 + lg * 4 + r;
                int col = n0 + wn * 64 + ni * 16 + lr;
                float val = acc[mi][ni][r];
                if (MODE == 0) {
                    float bias, scl;
                    if (col < 512)       { bias = bias_q[col];        scl = SCALE; }
                    else if (col < 1024) { bias = bias_k[col - 512];  scl = SCALE; }
                    else                 { bias = bias_v[col - 1024]; scl = 1.0f;  }
                    Cbf[(size_t)row * 1536 + col] = f2bf((val + bias) * scl);
                } else {
                    Cf[(size_t)row * 512 + col] =
                        val + bias_p[col] + resid[(size_t)row * 512 + col];
                }
            }
}

// ------------------------------------------------ V transpose to [b][d][n]
__global__ __launch_bounds__(256) void vtrans(
    const unsigned short* __restrict__ qkv, unsigned short* __restrict__ vT)
{
    int n0 = blockIdx.x * 64, d0 = blockIdx.y * 64, b = blockIdx.z;
    int t = threadIdx.x;
    __shared__ unsigned short tile[64][72];
    for (int c = 0; c < 2; ++c) {
        int flat = c * 256 + t;
        int r = flat >> 3, cc = (flat & 7) * 8;
        *(bf16x8*)&tile[r][cc] =
            *(const bf16x8*)&qkv[(size_t)(b * 4096 + n0 + r) * 1536 + 1024 + d0 + cc];
    }
    __syncthreads();
    for (int c = 0; c < 2; ++c) {
        int flat = c * 256 + t;
        int dr = flat >> 3, nc = (flat & 7) * 8;
        bf16x8 v;
        for (int j = 0; j < 8; ++j) v[j] = (short)tile[nc + j][dr];
        *(bf16x8*)&vT[((size_t)b * 512 + d0 + dr) * 4096 + n0 + nc] = v;
    }
}

// ------------------------------------------------------------ QK^T + exp v4
// TLP structure: 128x128 tile, 256 thr (4 waves 2x2), SINGLE-buffer 33 KB
// -> __launch_bounds__(256,3) = 3 blocks/CU co-resident; per-step stalls
// overlap across independent blocks (m97 mechanism) instead of pipelining.
// SWAPPED operands: A=K, B=Q -> acc holds S^T (rows=kv, cols=q):
//   - row-sum over kv is mostly IN-LANE (31 adds + 2 shfl per q)
//   - P->LDS as packed ds_write_b64 (4 consecutive kv per lane via cvt_pk)
// Grid 2048, XCD decode: per XCD 8 q-panels x 32 kv-panels (~5MB, L2-resident).
__global__ __launch_bounds__(256, 3) void qk_kernel(
    const unsigned short* __restrict__ qkv, unsigned short* __restrict__ P,
    float* __restrict__ lpart, int b0)
{
    int W = blockIdx.x;
    int xcd = W & 7, i = W >> 3;
    int bb = xcd >> 2;
    int nb = (xcd & 3) * 8 + (i & 7);   // q-block
    int mb = i >> 3;                    // kv-block
    int m0 = mb * 128, n0 = nb * 128;
    int b = b0 + bb;

    int t = threadIdx.x, l = t & 63, w = t >> 6;
    int wm = w >> 1, wn = w & 1;
    int lr = l & 15, lg = l >> 4;

    __shared__ __align__(16) unsigned short lds[16896];  // 33 KB
    unsigned short* As = lds;             // K tile 128x64 (kv rows)
    unsigned short* Bs = lds + 8192;      // Q tile 128x64 (q rows)
    float* Lw = (float*)(lds + 16384);    // 2 x 128 row-sum halves

    const unsigned short* A_ = qkv + (size_t)(b * 4096 + m0) * 1536 + 512;  // K
    const unsigned short* B_ = qkv + (size_t)(b * 4096 + n0) * 1536;        // Q

    auto stage = [&](int s) {
        int k0 = s * 64;
#pragma unroll
        for (int c = 0; c < 4; ++c) {
            int flat = c * 256 + t;       // 1024 units: 128 rows x 8
            int row = flat >> 3, u = flat & 7;
            g2l16(A_ + (size_t)row * 1536 + k0 + ((u ^ (row & 7)) << 3),
                  As + (flat << 3));
        }
#pragma unroll
        for (int c = 0; c < 4; ++c) {
            int flat = c * 256 + t;
            int row = flat >> 3, u = flat & 7;
            g2l16(B_ + (size_t)row * 1536 + k0 + ((u ^ (row & 7)) << 3),
                  Bs + (flat << 3));
        }
    };

    f32x4 acc[4][4];
#pragma unroll
    for (int mi = 0; mi < 4; ++mi)
#pragma unroll
        for (int ni = 0; ni < 4; ++ni) acc[mi][ni] = f32x4{0.f, 0.f, 0.f, 0.f};

    for (int s = 0; s < 8; ++s) {
        if (s) LGKM_BARRIER();             // all reads of buf retired
        stage(s);
        PHASE_BARRIER();                   // DMA landed
        __builtin_amdgcn_s_setprio(1);
#pragma unroll
        for (int ks = 0; ks < 2; ++ks) {
            bf16x8 af[4], bfr[4];
#pragma unroll
            for (int mi = 0; mi < 4; ++mi) {
                int row = wm * 64 + mi * 16 + lr;
                af[mi] = *(const bf16x8*)&As[(row * 8 + ((ks * 4 + lg) ^ (row & 7))) << 3];
            }
#pragma unroll
            for (int ni = 0; ni < 4; ++ni) {
                int row = wn * 64 + ni * 16 + lr;
                bfr[ni] = *(const bf16x8*)&Bs[(row * 8 + ((ks * 4 + lg) ^ (row & 7))) << 3];
            }
#pragma unroll
            for (int mi = 0; mi < 4; ++mi)
#pragma unroll
                for (int ni = 0; ni < 4; ++ni)
                    acc[mi][ni] = MFMA16(af[mi], bfr[ni], acc[mi][ni]);
        }
        __builtin_amdgcn_s_setprio(0);
    }
    LGKM_BARRIER();   // last compute's LDS reads retired -> buffers reusable

    // ---- epilogue: exp + in-lane row sums + packed P writes (S^T layout)
    // lane owns q = wn*64 + ni*16 + lr (per ni), kv = wm*64 + mi*16 + lg*4 + r
    unsigned short* Pl = lds;             // 128 q x 128 kv = 32 KB overlay
    {
        float sums[4] = {0.f, 0.f, 0.f, 0.f};
#pragma unroll
        for (int mi = 0; mi < 4; ++mi) {
            int u = wm * 8 + mi * 2 + (lg >> 1);   // 16B unit (16/row)
            int half = lg & 1;
#pragma unroll
            for (int ni = 0; ni < 4; ++ni) {
                float p0 = __expf(acc[mi][ni][0]);
                float p1 = __expf(acc[mi][ni][1]);
                float p2 = __expf(acc[mi][ni][2]);
                float p3 = __expf(acc[mi][ni][3]);
                sums[ni] += p0 + p1 + p2 + p3;
                int q = wn * 64 + ni * 16 + lr;
                unsigned* dst = (unsigned*)&((char*)Pl)[
                    q * 256 + ((u ^ (q & 7)) << 4) + (half << 3)];
                dst[0] = cvtpk(p0, p1);
                dst[1] = cvtpk(p2, p3);
            }
        }
        // reduce over lg (lanes 16/32 apart share q), then wm halves via LDS
#pragma unroll
        for (int ni = 0; ni < 4; ++ni) {
            float v = sums[ni];
            v += __shfl_xor(v, 16);
            v += __shfl_xor(v, 32);
            if (lg == 0) Lw[wm * 128 + wn * 64 + ni * 16 + lr] = v;
        }
    }
    LGKM_BARRIER();

    if (t < 128)
        lpart[(size_t)(bb * 32 + mb) * 4096 + n0 + t] = Lw[t] + Lw[128 + t];

    // coalesced P store: P[q_global][kv_global], 256 B per q-row
#pragma unroll
    for (int c = 0; c < 8; ++c) {
        int flat = c * 256 + t;            // 2048 units: 128 rows x 16
        int row = flat >> 4, u = flat & 15;
        *(bf16x8*)&P[((size_t)(bb * 4096 + n0 + row)) * 4096 + m0 + u * 8] =
            *(const bf16x8*)&((char*)Pl)[row * 256 + ((u ^ (row & 7)) << 4)];
    }
}

// ----------------------------------------------------- l reduce (32 slices)
__global__ __launch_bounds__(256) void lred_kernel(
    const float* __restrict__ lpart, float* __restrict__ lsum)
{
    int rr = blockIdx.x * 256 + threadIdx.x;  // 0..8191
    int bb = rr >> 12, r = rr & 4095;
    float s = 0.f;
#pragma unroll
    for (int sl = 0; sl < 32; ++sl)
        s += lpart[(size_t)(bb * 32 + sl) * 4096 + r];
    lsum[rr] = 1.0f / s;
}

// ------------------------------------------------------------ PV GEMM v2
// O[q][d] = (P . V) / l. 128x128 tile, 512 thr (8 waves = 2m x 4n of 64x32),
// grid (32,4,2) = 256 blocks = 1/CU. K=4096, BK=64 (64 steps).
// 3-buffer 2-ahead staging, counted vmcnt(4).
__global__ __launch_bounds__(512) void pv_kernel(
    const unsigned short* __restrict__ P, const unsigned short* __restrict__ vT,
    const float* __restrict__ linv, unsigned short* __restrict__ outb, int b0)
{
    int m0 = blockIdx.x * 128, n0 = blockIdx.y * 128, bb = blockIdx.z;
    int b = b0 + bb;
    int t = threadIdx.x, l = t & 63, w = t >> 6;
    int wm = w >> 2, wn = w & 3;
    int lr = l & 15, lg = l >> 4;

    __shared__ __align__(16) unsigned short lds[49152];  // 96 KB
    unsigned short* As = lds;           // 3 x 8192 (128 x 64)
    unsigned short* Bs = lds + 24576;   // 3 x 8192 (128 x 64)

    const unsigned short* A_ = P + (size_t)(bb * 4096 + m0) * 4096;
    const unsigned short* B_ = vT + ((size_t)b * 512 + n0) * 4096;

    auto stage = [&](int s, int buf) {   // 4 vmem instr per wave
        int k0 = s * 64;
        unsigned short* ad = As + buf * 8192;
        unsigned short* bd = Bs + buf * 8192;
#pragma unroll
        for (int c = 0; c < 2; ++c) {
            int flat = c * 512 + t;
            int row = flat >> 3, u = flat & 7;
            g2l16(A_ + (size_t)row * 4096 + k0 + ((u ^ (row & 7)) << 3),
                  ad + (flat << 3));
        }
#pragma unroll
        for (int c = 0; c < 2; ++c) {
            int flat = c * 512 + t;
            int row = flat >> 3, u = flat & 7;
            g2l16(B_ + (size_t)row * 4096 + k0 + ((u ^ (row & 7)) << 3),
                  bd + (flat << 3));
        }
    };

    f32x4 acc[4][2];
#pragma unroll
    for (int i = 0; i < 4; ++i)
#pragma unroll
        for (int j = 0; j < 2; ++j) acc[i][j] = f32x4{0.f, 0.f, 0.f, 0.f};

    stage(0, 0);
    stage(1, 1);
    asm volatile("s_waitcnt vmcnt(4)" ::: "memory");
    __builtin_amdgcn_s_barrier();
    __builtin_amdgcn_sched_barrier(0);

    for (int s = 0; s < 64; ++s) {
        if (s + 2 < 64) stage(s + 2, (s + 2) % 3);
        const unsigned short* Al = As + (s % 3) * 8192;
        const unsigned short* Bl = Bs + (s % 3) * 8192;
        __builtin_amdgcn_s_setprio(1);
#pragma unroll
        for (int ks = 0; ks < 2; ++ks) {
            bf16x8 af[4], bfr[2];
#pragma unroll
            for (int mi = 0; mi < 4; ++mi) {
                int row = wm * 64 + mi * 16 + lr;
                af[mi] = *(const bf16x8*)&Al[(row * 8 + ((ks * 4 + lg) ^ (row & 7))) << 3];
            }
#pragma unroll
            for (int ni = 0; ni < 2; ++ni) {
                int row = wn * 32 + ni * 16 + lr;
                bfr[ni] = *(const bf16x8*)&Bl[(row * 8 + ((ks * 4 + lg) ^ (row & 7))) << 3];
            }
#pragma unroll
            for (int mi = 0; mi < 4; ++mi)
#pragma unroll
                for (int ni = 0; ni < 2; ++ni)
                    acc[mi][ni] = MFMA16(af[mi], bfr[ni], acc[mi][ni]);
        }
        __builtin_amdgcn_s_setprio(0);
        if (s < 62) asm volatile("s_waitcnt vmcnt(4) lgkmcnt(0)" ::: "memory");
        else        asm volatile("s_waitcnt vmcnt(0) lgkmcnt(0)" ::: "memory");
        __builtin_amdgcn_s_barrier();
        __builtin_amdgcn_sched_barrier(0);
    }

#pragma unroll
    for (int mi = 0; mi < 4; ++mi)
#pragma unroll
        for (int r = 0; r < 4; ++r) {
            int row = m0 + wm * 64 + mi * 16 + lg * 4 + r;
            float inv = linv[bb * 4096 + row];
#pragma unroll
            for (int ni = 0; ni < 2; ++ni) {
                int col = n0 + wn * 32 + ni * 16 + lr;
                outb[(size_t)(b * 4096 + row) * 512 + col] =
                    f2bf(acc[mi][ni][r] * inv);
            }
        }
}

// --------------------------------------------------------------- launcher
extern "C" void kernel_launch(void* const* d_in, const int* in_sizes, int n_in,
                              void* d_out, int out_size, void* d_ws, size_t ws_size,
                              hipStream_t stream)
{
    const float* x     = (const float*)d_in[0];
    const float* gamma = (const float*)d_in[1];
    const float* beta  = (const float*)d_in[2];
    const float* Wq = (const float*)d_in[3];
    const float* bq = (const float*)d_in[4];
    const float* Wk = (const float*)d_in[5];
    const float* bk = (const float*)d_in[6];
    const float* Wv = (const float*)d_in[7];
    const float* bv = (const float*)d_in[8];
    const float* Wp = (const float*)d_in[9];
    const float* bp = (const float*)d_in[10];
    float* out = (float*)d_out;

    unsigned short* xn    = (unsigned short*)d_ws;                 // 16384*512 (reused as attn out)
    unsigned short* wqkvt = xn + (size_t)16384 * 512;              // 1536*512
    unsigned short* wpt   = wqkvt + (size_t)1536 * 512;            // 512*512
    unsigned short* qkv   = wpt + (size_t)512 * 512;               // 16384*1536
    unsigned short* vT    = qkv + (size_t)16384 * 1536;            // 4*512*4096
    unsigned short* P     = vT + (size_t)4 * 512 * 4096;           // 2*4096*4096 (64MB)
    float* lpart = (float*)(P + (size_t)2 * 4096 * 4096);          // 64*4096 f32
    float* linv  = lpart + (size_t)128 * 4096;                     // 8192 f32

    gn_kernel<<<dim3(128), dim3(256), 0, stream>>>(x, gamma, beta, xn);
    wprep<<<dim3(4096), dim3(256), 0, stream>>>(Wq, Wk, Wv, Wp, wqkvt, wpt);
    gemm_kernel<0><<<dim3(128, 12), dim3(256), 0, stream>>>(
        xn, wqkvt, bq, bk, bv, nullptr, nullptr, qkv, nullptr);
    vtrans<<<dim3(64, 8, 4), dim3(256), 0, stream>>>(qkv, vT);

    for (int b0 = 0; b0 < 4; b0 += 2) {
        qk_kernel<<<dim3(2048), dim3(256), 0, stream>>>(qkv, P, lpart, b0);
        lred_kernel<<<dim3(32), dim3(256), 0, stream>>>(lpart, linv);
        pv_kernel<<<dim3(32, 4, 2), dim3(512), 0, stream>>>(P, vT, linv, xn, b0);
    }

    gemm_kernel<1><<<dim3(128, 4), dim3(256), 0, stream>>>(
        xn, wpt, nullptr, nullptr, nullptr, bp, x, nullptr, out);
}

// Round 12
// 252.817 us; speedup vs baseline: 1.9611x; 1.1244x over previous
//
#include <hip/hip_runtime.h>
#include <hip/hip_bf16.h>

typedef __attribute__((ext_vector_type(8))) short bf16x8;
typedef __attribute__((ext_vector_type(4))) float f32x4;
typedef __attribute__((ext_vector_type(4))) unsigned short u16x4;

#define MFMA16(a, b, c) __builtin_amdgcn_mfma_f32_16x16x32_bf16(a, b, c, 0, 0, 0)

#define SCALE 0.21022410381342865f /* 512^(-1/4) */

__device__ __forceinline__ unsigned short f2bf(float f) {
    union { float f; unsigned u; } v; v.f = f;
    unsigned r = v.u + 0x7FFF + ((v.u >> 16) & 1);
    return (unsigned short)(r >> 16);
}

__device__ __forceinline__ unsigned cvtpk(float lo, float hi) {
    unsigned r;
    asm("v_cvt_pk_bf16_f32 %0, %1, %2" : "=v"(r) : "v"(lo), "v"(hi));
    return r;
}

typedef __attribute__((address_space(3))) void lds_void;
typedef const __attribute__((address_space(1))) void gbl_void;
__device__ __forceinline__ void g2l16(const void* g, void* l) {
    __builtin_amdgcn_global_load_lds((gbl_void*)g, (lds_void*)l, 16, 0, 0);
}

#define PHASE_BARRIER() do { \
    asm volatile("s_waitcnt vmcnt(0) lgkmcnt(0)" ::: "memory"); \
    __builtin_amdgcn_s_barrier(); \
    __builtin_amdgcn_sched_barrier(0); \
} while (0)

#define LGKM_BARRIER() do { \
    asm volatile("s_waitcnt lgkmcnt(0)" ::: "memory"); \
    __builtin_amdgcn_s_barrier(); \
    __builtin_amdgcn_sched_barrier(0); \
} while (0)

// ------------------------------------------------------- GroupNorm stats
// grid 1024: (b 0..3, g 0..31, slice 0..7); each block reduces 8192 elems.
__global__ __launch_bounds__(256) void gn_stats(
    const float* __restrict__ x, float2* __restrict__ gstats)
{
    int id = blockIdx.x;
    int b = id >> 8, rem = id & 255;
    int g = rem >> 3, sl = rem & 7;
    int t = threadIdx.x;
    const float4* xf4 = (const float4*)x;
    size_t base4 = (size_t)b * (4096 * 128) + g * 4;

    float s = 0.f, ss = 0.f;
#pragma unroll
    for (int i = 0; i < 8; ++i) {
        int flat = i * 256 + t;
        int hw = sl * 512 + (flat >> 2), c4 = flat & 3;
        float4 v = xf4[base4 + (size_t)hw * 128 + c4];
        s  += v.x + v.y + v.z + v.w;
        ss += v.x * v.x + v.y * v.y + v.z * v.z + v.w * v.w;
    }
    for (int m = 32; m >= 1; m >>= 1) { s += __shfl_xor(s, m); ss += __shfl_xor(ss, m); }
    __shared__ float rs_[4], rss_[4];
    int wv = t >> 6;
    if ((t & 63) == 0) { rs_[wv] = s; rss_[wv] = ss; }
    __syncthreads();
    if (t == 0) {
        float2 o;
        o.x = rs_[0] + rs_[1] + rs_[2] + rs_[3];
        o.y = rss_[0] + rss_[1] + rss_[2] + rss_[3];
        gstats[id] = o;
    }
}

// ------------------------------------------------------- GroupNorm apply
// grid 2048: (b, g, slice 0..15); reduce the 8 partials inline (broadcast).
__global__ __launch_bounds__(256) void gn_apply(
    const float* __restrict__ x, const float* __restrict__ gamma,
    const float* __restrict__ beta, const float2* __restrict__ gstats,
    unsigned short* __restrict__ xn)
{
    int id = blockIdx.x;
    int b = id >> 9, rem = id & 511;
    int g = rem >> 4, sl = rem & 15;
    int t = threadIdx.x;

    float s = 0.f, ss = 0.f;
#pragma unroll
    for (int i = 0; i < 8; ++i) {
        float2 p = gstats[(b * 32 + g) * 8 + i];
        s += p.x; ss += p.y;
    }
    float mean = s * (1.f / 65536.f);
    float var  = ss * (1.f / 65536.f) - mean * mean;
    float rstd = rsqrtf(var + 1e-6f);

    const float4* xf4 = (const float4*)x;
    const float4* g4 = (const float4*)gamma;
    const float4* b4 = (const float4*)beta;
    size_t base4 = (size_t)b * (4096 * 128) + g * 4;
#pragma unroll
    for (int i = 0; i < 4; ++i) {
        int flat = i * 256 + t;
        int hw = sl * 256 + (flat >> 2), c4 = flat & 3;
        float4 v  = xf4[base4 + (size_t)hw * 128 + c4];
        float4 gm = g4[g * 4 + c4], bt = b4[g * 4 + c4];
        u16x4 o;
        o.x = f2bf((v.x - mean) * rstd * gm.x + bt.x);
        o.y = f2bf((v.y - mean) * rstd * gm.y + bt.y);
        o.z = f2bf((v.z - mean) * rstd * gm.z + bt.z);
        o.w = f2bf((v.w - mean) * rstd * gm.w + bt.w);
        *(u16x4*)&xn[(size_t)(b * 4096 + hw) * 512 + g * 16 + c4 * 4] = o;
    }
}

// ------------------------------------------------- weight prep: W^T as bf16
__global__ __launch_bounds__(256) void wprep(
    const float* __restrict__ Wq, const float* __restrict__ Wk,
    const float* __restrict__ Wv, const float* __restrict__ Wp,
    unsigned short* __restrict__ wqkvt, unsigned short* __restrict__ wpt)
{
    int idx = blockIdx.x * 256 + threadIdx.x; // 1,048,576 total
    if (idx < 786432) {
        int n = idx >> 9, k = idx & 511;
        int j = n >> 9, nn = n & 511;
        const float* W = (j == 0) ? Wq : (j == 1) ? Wk : Wv;
        wqkvt[idx] = f2bf(W[k * 512 + nn]);
    } else {
        int i2 = idx - 786432;
        int n = i2 >> 9, k = i2 & 511;
        wpt[i2] = f2bf(Wp[k * 512 + n]);
    }
}

// ------------------------------------------------------------- bf16 GEMM v2
// qk-v4 skeleton: 128x128 tile, 256 thr (4 waves 2x2), single 32 KB buffer,
// g2l16 DMA staging, XOR swizzle, 3 blocks/CU TLP. K = 512 (8 steps).
template <int MODE>
__global__ __launch_bounds__(256, 3) void gemm_kernel(
    const unsigned short* __restrict__ A, const unsigned short* __restrict__ Bt,
    const float* __restrict__ bias_q, const float* __restrict__ bias_k,
    const float* __restrict__ bias_v, const float* __restrict__ bias_p,
    const float* __restrict__ resid,
    unsigned short* __restrict__ Cbf, float* __restrict__ Cf)
{
    int m0 = blockIdx.x * 128;
    int n0 = blockIdx.y * 128;
    int t = threadIdx.x;
    int l = t & 63, w = t >> 6;
    int wm = w >> 1, wn = w & 1;
    int lr = l & 15, lg = l >> 4;

    __shared__ __align__(16) unsigned short lds[16384];  // 32 KB
    unsigned short* As = lds;
    unsigned short* Bs = lds + 8192;

    const unsigned short* A_ = A + (size_t)m0 * 512;
    const unsigned short* B_ = Bt + (size_t)n0 * 512;

    auto stage = [&](int s) {
        int k0 = s * 64;
#pragma unroll
        for (int c = 0; c < 4; ++c) {
            int flat = c * 256 + t;
            int row = flat >> 3, u = flat & 7;
            g2l16(A_ + (size_t)row * 512 + k0 + ((u ^ (row & 7)) << 3),
                  As + (flat << 3));
        }
#pragma unroll
        for (int c = 0; c < 4; ++c) {
            int flat = c * 256 + t;
            int row = flat >> 3, u = flat & 7;
            g2l16(B_ + (size_t)row * 512 + k0 + ((u ^ (row & 7)) << 3),
                  Bs + (flat << 3));
        }
    };

    f32x4 acc[4][4];
#pragma unroll
    for (int i = 0; i < 4; ++i)
#pragma unroll
        for (int j = 0; j < 4; ++j) acc[i][j] = f32x4{0.f, 0.f, 0.f, 0.f};

    for (int s = 0; s < 8; ++s) {
        if (s) LGKM_BARRIER();
        stage(s);
        PHASE_BARRIER();
        __builtin_amdgcn_s_setprio(1);
#pragma unroll
        for (int ks = 0; ks < 2; ++ks) {
            bf16x8 af[4], bfr[4];
#pragma unroll
            for (int mi = 0; mi < 4; ++mi) {
                int row = wm * 64 + mi * 16 + lr;
                af[mi] = *(const bf16x8*)&As[(row * 8 + ((ks * 4 + lg) ^ (row & 7))) << 3];
            }
#pragma unroll
            for (int ni = 0; ni < 4; ++ni) {
                int row = wn * 64 + ni * 16 + lr;
                bfr[ni] = *(const bf16x8*)&Bs[(row * 8 + ((ks * 4 + lg) ^ (row & 7))) << 3];
            }
#pragma unroll
            for (int mi = 0; mi < 4; ++mi)
#pragma unroll
                for (int ni = 0; ni < 4; ++ni)
                    acc[mi][ni] = MFMA16(af[mi], bfr[ni], acc[mi][ni]);
        }
        __builtin_amdgcn_s_setprio(0);
    }

#pragma unroll
    for (int mi = 0; mi < 4; ++mi)
#pragma unroll
        for (int ni = 0; ni < 4; ++ni)
#pragma unroll
            for (int r = 0; r < 4; ++r) {
                int row = m0 + wm * 64 + mi * 16 + lg * 4 + r;
                int col = n0 + wn * 64 + ni * 16 + lr;
                float val = acc[mi][ni][r];
                if (MODE == 0) {
                    float bias, scl;
                    if (col < 512)       { bias = bias_q[col];        scl = SCALE; }
                    else if (col < 1024) { bias = bias_k[col - 512];  scl = SCALE; }
                    else                 { bias = bias_v[col - 1024]; scl = 1.0f;  }
                    Cbf[(size_t)row * 1536 + col] = f2bf((val + bias) * scl);
                } else {
                    Cf[(size_t)row * 512 + col] =
                        val + bias_p[col] + resid[(size_t)row * 512 + col];
                }
            }
}

// ------------------------------------------------ V transpose to [b][d][n]
__global__ __launch_bounds__(256) void vtrans(
    const unsigned short* __restrict__ qkv, unsigned short* __restrict__ vT)
{
    int n0 = blockIdx.x * 64, d0 = blockIdx.y * 64, b = blockIdx.z;
    int t = threadIdx.x;
    __shared__ unsigned short tile[64][72];
    for (int c = 0; c < 2; ++c) {
        int flat = c * 256 + t;
        int r = flat >> 3, cc = (flat & 7) * 8;
        *(bf16x8*)&tile[r][cc] =
            *(const bf16x8*)&qkv[(size_t)(b * 4096 + n0 + r) * 1536 + 1024 + d0 + cc];
    }
    __syncthreads();
    for (int c = 0; c < 2; ++c) {
        int flat = c * 256 + t;
        int dr = flat >> 3, nc = (flat & 7) * 8;
        bf16x8 v;
        for (int j = 0; j < 8; ++j) v[j] = (short)tile[nc + j][dr];
        *(bf16x8*)&vT[((size_t)b * 512 + d0 + dr) * 4096 + n0 + nc] = v;
    }
}

// ------------------------------------------------------------ QK^T + exp v4
__global__ __launch_bounds__(256, 3) void qk_kernel(
    const unsigned short* __restrict__ qkv, unsigned short* __restrict__ P,
    float* __restrict__ lpart, int b0)
{
    int W = blockIdx.x;
    int xcd = W & 7, i = W >> 3;
    int bb = xcd >> 2;
    int nb = (xcd & 3) * 8 + (i & 7);   // q-block
    int mb = i >> 3;                    // kv-block
    int m0 = mb * 128, n0 = nb * 128;
    int b = b0 + bb;

    int t = threadIdx.x, l = t & 63, w = t >> 6;
    int wm = w >> 1, wn = w & 1;
    int lr = l & 15, lg = l >> 4;

    __shared__ __align__(16) unsigned short lds[16896];  // 33 KB
    unsigned short* As = lds;             // K tile 128x64 (kv rows)
    unsigned short* Bs = lds + 8192;      // Q tile 128x64 (q rows)
    float* Lw = (float*)(lds + 16384);    // 2 x 128 row-sum halves

    const unsigned short* A_ = qkv + (size_t)(b * 4096 + m0) * 1536 + 512;  // K
    const unsigned short* B_ = qkv + (size_t)(b * 4096 + n0) * 1536;        // Q

    auto stage = [&](int s) {
        int k0 = s * 64;
#pragma unroll
        for (int c = 0; c < 4; ++c) {
            int flat = c * 256 + t;       // 1024 units: 128 rows x 8
            int row = flat >> 3, u = flat & 7;
            g2l16(A_ + (size_t)row * 1536 + k0 + ((u ^ (row & 7)) << 3),
                  As + (flat << 3));
        }
#pragma unroll
        for (int c = 0; c < 4; ++c) {
            int flat = c * 256 + t;
            int row = flat >> 3, u = flat & 7;
            g2l16(B_ + (size_t)row * 1536 + k0 + ((u ^ (row & 7)) << 3),
                  Bs + (flat << 3));
        }
    };

    f32x4 acc[4][4];
#pragma unroll
    for (int mi = 0; mi < 4; ++mi)
#pragma unroll
        for (int ni = 0; ni < 4; ++ni) acc[mi][ni] = f32x4{0.f, 0.f, 0.f, 0.f};

    for (int s = 0; s < 8; ++s) {
        if (s) LGKM_BARRIER();             // all reads of buf retired
        stage(s);
        PHASE_BARRIER();                   // DMA landed
        __builtin_amdgcn_s_setprio(1);
#pragma unroll
        for (int ks = 0; ks < 2; ++ks) {
            bf16x8 af[4], bfr[4];
#pragma unroll
            for (int mi = 0; mi < 4; ++mi) {
                int row = wm * 64 + mi * 16 + lr;
                af[mi] = *(const bf16x8*)&As[(row * 8 + ((ks * 4 + lg) ^ (row & 7))) << 3];
            }
#pragma unroll
            for (int ni = 0; ni < 4; ++ni) {
                int row = wn * 64 + ni * 16 + lr;
                bfr[ni] = *(const bf16x8*)&Bs[(row * 8 + ((ks * 4 + lg) ^ (row & 7))) << 3];
            }
#pragma unroll
            for (int mi = 0; mi < 4; ++mi)
#pragma unroll
                for (int ni = 0; ni < 4; ++ni)
                    acc[mi][ni] = MFMA16(af[mi], bfr[ni], acc[mi][ni]);
        }
        __builtin_amdgcn_s_setprio(0);
    }
    LGKM_BARRIER();   // last compute's LDS reads retired -> buffers reusable

    // ---- epilogue: exp + in-lane row sums + packed P writes (S^T layout)
    unsigned short* Pl = lds;             // 128 q x 128 kv = 32 KB overlay
    {
        float sums[4] = {0.f, 0.f, 0.f, 0.f};
#pragma unroll
        for (int mi = 0; mi < 4; ++mi) {
            int u = wm * 8 + mi * 2 + (lg >> 1);   // 16B unit (16/row)
            int half = lg & 1;
#pragma unroll
            for (int ni = 0; ni < 4; ++ni) {
                float p0 = __expf(acc[mi][ni][0]);
                float p1 = __expf(acc[mi][ni][1]);
                float p2 = __expf(acc[mi][ni][2]);
                float p3 = __expf(acc[mi][ni][3]);
                sums[ni] += p0 + p1 + p2 + p3;
                int q = wn * 64 + ni * 16 + lr;
                unsigned* dst = (unsigned*)&((char*)Pl)[
                    q * 256 + ((u ^ (q & 7)) << 4) + (half << 3)];
                dst[0] = cvtpk(p0, p1);
                dst[1] = cvtpk(p2, p3);
            }
        }
#pragma unroll
        for (int ni = 0; ni < 4; ++ni) {
            float v = sums[ni];
            v += __shfl_xor(v, 16);
            v += __shfl_xor(v, 32);
            if (lg == 0) Lw[wm * 128 + wn * 64 + ni * 16 + lr] = v;
        }
    }
    LGKM_BARRIER();

    if (t < 128)
        lpart[(size_t)(bb * 32 + mb) * 4096 + n0 + t] = Lw[t] + Lw[128 + t];

    // coalesced P store: P[q_global][kv_global], 256 B per q-row
#pragma unroll
    for (int c = 0; c < 8; ++c) {
        int flat = c * 256 + t;            // 2048 units: 128 rows x 16
        int row = flat >> 4, u = flat & 15;
        *(bf16x8*)&P[((size_t)(bb * 4096 + n0 + row)) * 4096 + m0 + u * 8] =
            *(const bf16x8*)&((char*)Pl)[row * 256 + ((u ^ (row & 7)) << 4)];
    }
}

// ----------------------------------------------------- l reduce (32 slices)
__global__ __launch_bounds__(256) void lred_kernel(
    const float* __restrict__ lpart, float* __restrict__ lsum)
{
    int rr = blockIdx.x * 256 + threadIdx.x;  // 0..8191
    int bb = rr >> 12, r = rr & 4095;
    float s = 0.f;
#pragma unroll
    for (int sl = 0; sl < 32; ++sl)
        s += lpart[(size_t)(bb * 32 + sl) * 4096 + r];
    lsum[rr] = 1.0f / s;
}

// ------------------------------------------------------------ PV GEMM v2
__global__ __launch_bounds__(512) void pv_kernel(
    const unsigned short* __restrict__ P, const unsigned short* __restrict__ vT,
    const float* __restrict__ linv, unsigned short* __restrict__ outb, int b0)
{
    int m0 = blockIdx.x * 128, n0 = blockIdx.y * 128, bb = blockIdx.z;
    int b = b0 + bb;
    int t = threadIdx.x, l = t & 63, w = t >> 6;
    int wm = w >> 2, wn = w & 3;
    int lr = l & 15, lg = l >> 4;

    __shared__ __align__(16) unsigned short lds[49152];  // 96 KB
    unsigned short* As = lds;           // 3 x 8192 (128 x 64)
    unsigned short* Bs = lds + 24576;   // 3 x 8192 (128 x 64)

    const unsigned short* A_ = P + (size_t)(bb * 4096 + m0) * 4096;
    const unsigned short* B_ = vT + ((size_t)b * 512 + n0) * 4096;

    auto stage = [&](int s, int buf) {   // 4 vmem instr per wave
        int k0 = s * 64;
        unsigned short* ad = As + buf * 8192;
        unsigned short* bd = Bs + buf * 8192;
#pragma unroll
        for (int c = 0; c < 2; ++c) {
            int flat = c * 512 + t;
            int row = flat >> 3, u = flat & 7;
            g2l16(A_ + (size_t)row * 4096 + k0 + ((u ^ (row & 7)) << 3),
                  ad + (flat << 3));
        }
#pragma unroll
        for (int c = 0; c < 2; ++c) {
            int flat = c * 512 + t;
            int row = flat >> 3, u = flat & 7;
            g2l16(B_ + (size_t)row * 4096 + k0 + ((u ^ (row & 7)) << 3),
                  bd + (flat << 3));
        }
    };

    f32x4 acc[4][2];
#pragma unroll
    for (int i = 0; i < 4; ++i)
#pragma unroll
        for (int j = 0; j < 2; ++j) acc[i][j] = f32x4{0.f, 0.f, 0.f, 0.f};

    stage(0, 0);
    stage(1, 1);
    asm volatile("s_waitcnt vmcnt(4)" ::: "memory");
    __builtin_amdgcn_s_barrier();
    __builtin_amdgcn_sched_barrier(0);

    for (int s = 0; s < 64; ++s) {
        if (s + 2 < 64) stage(s + 2, (s + 2) % 3);
        const unsigned short* Al = As + (s % 3) * 8192;
        const unsigned short* Bl = Bs + (s % 3) * 8192;
        __builtin_amdgcn_s_setprio(1);
#pragma unroll
        for (int ks = 0; ks < 2; ++ks) {
            bf16x8 af[4], bfr[2];
#pragma unroll
            for (int mi = 0; mi < 4; ++mi) {
                int row = wm * 64 + mi * 16 + lr;
                af[mi] = *(const bf16x8*)&Al[(row * 8 + ((ks * 4 + lg) ^ (row & 7))) << 3];
            }
#pragma unroll
            for (int ni = 0; ni < 2; ++ni) {
                int row = wn * 32 + ni * 16 + lr;
                bfr[ni] = *(const bf16x8*)&Bl[(row * 8 + ((ks * 4 + lg) ^ (row & 7))) << 3];
            }
#pragma unroll
            for (int mi = 0; mi < 4; ++mi)
#pragma unroll
                for (int ni = 0; ni < 2; ++ni)
                    acc[mi][ni] = MFMA16(af[mi], bfr[ni], acc[mi][ni]);
        }
        __builtin_amdgcn_s_setprio(0);
        if (s < 62) asm volatile("s_waitcnt vmcnt(4) lgkmcnt(0)" ::: "memory");
        else        asm volatile("s_waitcnt vmcnt(0) lgkmcnt(0)" ::: "memory");
        __builtin_amdgcn_s_barrier();
        __builtin_amdgcn_sched_barrier(0);
    }

#pragma unroll
    for (int mi = 0; mi < 4; ++mi)
#pragma unroll
        for (int r = 0; r < 4; ++r) {
            int row = m0 + wm * 64 + mi * 16 + lg * 4 + r;
            float inv = linv[bb * 4096 + row];
#pragma unroll
            for (int ni = 0; ni < 2; ++ni) {
                int col = n0 + wn * 32 + ni * 16 + lr;
                outb[(size_t)(b * 4096 + row) * 512 + col] =
                    f2bf(acc[mi][ni][r] * inv);
            }
        }
}

// --------------------------------------------------------------- launcher
extern "C" void kernel_launch(void* const* d_in, const int* in_sizes, int n_in,
                              void* d_out, int out_size, void* d_ws, size_t ws_size,
                              hipStream_t stream)
{
    const float* x     = (const float*)d_in[0];
    const float* gamma = (const float*)d_in[1];
    const float* beta  = (const float*)d_in[2];
    const float* Wq = (const float*)d_in[3];
    const float* bq = (const float*)d_in[4];
    const float* Wk = (const float*)d_in[5];
    const float* bk = (const float*)d_in[6];
    const float* Wv = (const float*)d_in[7];
    const float* bv = (const float*)d_in[8];
    const float* Wp = (const float*)d_in[9];
    const float* bp = (const float*)d_in[10];
    float* out = (float*)d_out;

    unsigned short* xn    = (unsigned short*)d_ws;                 // 16384*512 (reused as attn out)
    unsigned short* wqkvt = xn + (size_t)16384 * 512;              // 1536*512
    unsigned short* wpt   = wqkvt + (size_t)1536 * 512;            // 512*512
    unsigned short* qkv   = wpt + (size_t)512 * 512;               // 16384*1536
    unsigned short* vT    = qkv + (size_t)16384 * 1536;            // 4*512*4096
    unsigned short* P     = vT + (size_t)4 * 512 * 4096;           // 2*4096*4096 (64MB)
    float* lpart = (float*)(P + (size_t)2 * 4096 * 4096);          // 64*4096 f32
    float* linv  = lpart + (size_t)128 * 4096;                     // 8192 f32
    float2* gstats = (float2*)(linv + 8192);                       // 1024 float2

    gn_stats<<<dim3(1024), dim3(256), 0, stream>>>(x, gstats);
    gn_apply<<<dim3(2048), dim3(256), 0, stream>>>(x, gamma, beta, gstats, xn);
    wprep<<<dim3(4096), dim3(256), 0, stream>>>(Wq, Wk, Wv, Wp, wqkvt, wpt);
    gemm_kernel<0><<<dim3(128, 12), dim3(256), 0, stream>>>(
        xn, wqkvt, bq, bk, bv, nullptr, nullptr, qkv, nullptr);
    vtrans<<<dim3(64, 8, 4), dim3(256), 0, stream>>>(qkv, vT);

    for (int b0 = 0; b0 < 4; b0 += 2) {
        qk_kernel<<<dim3(2048), dim3(256), 0, stream>>>(qkv, P, lpart, b0);
        lred_kernel<<<dim3(32), dim3(256), 0, stream>>>(lpart, linv);
        pv_kernel<<<dim3(32, 4, 2), dim3(512), 0, stream>>>(P, vT, linv, xn, b0);
    }

    gemm_kernel<1><<<dim3(128, 4), dim3(256), 0, stream>>>(
        xn, wpt, nullptr, nullptr, nullptr, bp, x, nullptr, out);
}